// Round 4
// baseline (1190.047 us; speedup 1.0000x reference)
//
#include <hip/hip_runtime.h>

// Problem constants (reference: B=2, T=2048, C=1024, V=8192, L=2, H=16, d=64)
#define BB 2
#define TT 2048
#define CC 1024
#define VV 8192
#define LL 2
#define HH 16
#define DD 64
#define MM (BB * TT) // 4096 rows

// R7b: vectorized GEMM epilogue (R7 retry; fixed nontemporal builtin types —
// it requires ext_vector_type pointers, not HIP_vector_type float4/uint2).
// R6 counters: logits gemm 328us with WRITE_SIZE 1.09GB for a 134MB output
// (8x partial-sector write amplification from scalar C-layout stores) +
// write-allocate fetch; MfmaUtil 8.5%. Fix: transpose acc through LDS (reuse
// As/Bs after K-loop; per-wave 16x68-float padded scratch) so each lane
// stores 16B (fp32) / 8B (bf16) of CONSECUTIVE columns -> dwordx4/x2 stores,
// full 64B sectors; nontemporal for logits.
using u16 = unsigned short;

typedef short bf16x8 __attribute__((ext_vector_type(8)));   // 8 bf16 = 4 VGPRs
typedef float f32x4 __attribute__((ext_vector_type(4)));    // MFMA accumulator
typedef unsigned int u32x2 __attribute__((ext_vector_type(2)));

__device__ __forceinline__ float bf2f(u16 u) {
    union { unsigned int i; float f; } x;
    x.i = ((unsigned int)u) << 16;
    return x.f;
}
__device__ __forceinline__ u16 f2bf(float f) {
    union { float f; unsigned int i; } x;
    x.f = f;
    unsigned int r = x.i + 0x7fffu + ((x.i >> 16) & 1u); // round-to-nearest-even
    return (u16)(r >> 16);
}

// ---------- 0. dtype probe (resolves fp32-vs-bf16 at runtime) ----------
__global__ __launch_bounds__(256) void probe_kernel(const u16* __restrict__ w,
                                                    int* __restrict__ flag) {
    __shared__ int cnt;
    if (threadIdx.x == 0) cnt = 0;
    __syncthreads();
    int c = 0;
    for (int i = threadIdx.x; i < 4096; i += 256) {
        const u16 u = w[2 * i];
        const int e = (u >> 7) & 0xff;
        if (e >= 125) ++c;
    }
    atomicAdd(&cnt, c);
    __syncthreads();
    if (threadIdx.x == 0) *flag = (cnt > 64) ? 1 : 0;
}

// ---------- 1. embedding + positional -> bf16 h ----------
__global__ __launch_bounds__(256) void embed_kernel(const int* __restrict__ x,
                                                    const void* __restrict__ ew,
                                                    const void* __restrict__ pos,
                                                    u16* __restrict__ h,
                                                    const int* __restrict__ flagp) {
    const int f = *flagp;
    const int i = blockIdx.x;        // token row 0..MM-1
    const int t = i & (TT - 1);      // position within sequence
    const int row = x[i];
    const int c = threadIdx.x * 4;
    float4 e, p;
    if (f) {
        e = *(const float4*)((const float*)ew + (size_t)row * CC + c);
        p = *(const float4*)((const float*)pos + (size_t)t * CC + c);
    } else {
        ushort4 eu = *(const ushort4*)((const u16*)ew + (size_t)row * CC + c);
        ushort4 pu = *(const ushort4*)((const u16*)pos + (size_t)t * CC + c);
        e = make_float4(bf2f(eu.x), bf2f(eu.y), bf2f(eu.z), bf2f(eu.w));
        p = make_float4(bf2f(pu.x), bf2f(pu.y), bf2f(pu.z), bf2f(pu.w));
    }
    ushort4 o;
    o.x = f2bf(e.x + p.x); o.y = f2bf(e.y + p.y);
    o.z = f2bf(e.z + p.z); o.w = f2bf(e.w + p.w);
    *(ushort4*)&h[(size_t)i * CC + c] = o;
}

// ---------- 1b. weight convert: fp32 -> bf16 (or bf16 copy) ----------
// onlyF=1: write only when flag==1 (dst scratch exists only in fp32 mode).
__global__ __launch_bounds__(256) void cvt_w(const void* __restrict__ src,
                                             u16* __restrict__ dst,
                                             int onlyF,
                                             const int* __restrict__ flagp) {
    const int f = *flagp;
    const size_t i = ((size_t)blockIdx.x * 256 + threadIdx.x) * 8;
    if (f) {
        const float* s = (const float*)src + i;
        float4 a = *(const float4*)s;
        float4 b = *(const float4*)(s + 4);
        uint4 o;
        o.x = (unsigned)f2bf(a.x) | ((unsigned)f2bf(a.y) << 16);
        o.y = (unsigned)f2bf(a.z) | ((unsigned)f2bf(a.w) << 16);
        o.z = (unsigned)f2bf(b.x) | ((unsigned)f2bf(b.y) << 16);
        o.w = (unsigned)f2bf(b.z) | ((unsigned)f2bf(b.w) << 16);
        *(uint4*)(dst + i) = o;
    } else if (!onlyF) {
        *(uint4*)(dst + i) = *(const uint4*)((const u16*)src + i);
    }
}

// ---------- 2. MFMA GEMM: out[m,n] = sum_k A[m,k]*W[n,k] (+bias[n]) (+res[m,n]) ----------
// A bf16 [M,K]; Wc bf16 [N,K] (converted scratch). If Walt!=null and flag==0,
// W = Walt (native bf16 weights, no scratch copy in bf16 mode).
// 128x128 tile, BK=64, 256 threads = 4 waves, each wave a 64x64 sub-tile
// (4x4 f32x4 accumulators). LDS rows are 128B (64 bf16); octet o (16B) of row
// r stored at slot o^(r&7) -> every ds_read_b128/ds_write_b128 spreads 8
// lanes over each of the 8 slot-columns = all 32 banks balanced (BW floor).
// MFMA layouts (validated by flash_attn): A row=lane&15,k=(lane>>4)*8+j;
// B col=lane&15 (same); C col=lane&15, row=(lane>>4)*4+reg.
// Epilogue: acc transposed through per-wave padded LDS scratch (16x68 f32)
// so stores are dwordx4/x2 per lane, full 64B HBM sectors.
__global__ __launch_bounds__(256) void gemm_bf16(const u16* __restrict__ A,
                                                 const u16* __restrict__ Wc,
                                                 const void* __restrict__ Walt,
                                                 void* __restrict__ outP,
                                                 const void* __restrict__ bias, size_t bOff,
                                                 const u16* __restrict__ res,
                                                 int M, int N, int K, int outFlagged,
                                                 const int* __restrict__ flagp) {
    const int f = *flagp;
    const u16* W = (Walt && !f) ? (const u16*)Walt : Wc;

    __shared__ u16 smemU[2][128 * 64];   // 32 KB: As | Bs, reused by epilogue
    u16* As = smemU[0];
    u16* Bs = smemU[1];
    char* AsB = (char*)As;
    char* BsB = (char*)Bs;

    const int tid = threadIdx.x;
    const int w = tid >> 6, lane = tid & 63, l15 = lane & 15, l4 = lane >> 4;
    const int m0 = blockIdx.y * 128, n0 = blockIdx.x * 128;
    const int wr = (w >> 1) * 64, wc = (w & 1) * 64;   // wave sub-tile origin

    // staging: thread -> row sr (0..127), octet group og = (tid&1)*4 .. +3
    const int sr = tid >> 1;
    const int og = (tid & 1) * 4;
    const size_t aRow = (size_t)(m0 + sr) * K + og * 8;
    const size_t wRow = (size_t)(n0 + sr) * K + og * 8;
    int dOff[4];
#pragma unroll
    for (int j = 0; j < 4; ++j)
        dOff[j] = sr * 128 + (((og + j) ^ (sr & 7)) << 4);

    f32x4 acc[4][4] = {};

    // prologue: load tile kt=0 into regs
    uint4 aR[4], wR[4];
#pragma unroll
    for (int j = 0; j < 4; ++j) {
        aR[j] = *(const uint4*)(A + aRow + j * 8);
        wR[j] = *(const uint4*)(W + wRow + j * 8);
    }

    for (int kt = 0; kt < K; kt += 64) {
        __syncthreads();            // previous tile fully consumed
#pragma unroll
        for (int j = 0; j < 4; ++j) *(uint4*)(AsB + dOff[j]) = aR[j];
#pragma unroll
        for (int j = 0; j < 4; ++j) *(uint4*)(BsB + dOff[j]) = wR[j];
        __syncthreads();
        if (kt + 64 < K) {          // issue next-tile loads; hide under MFMA
#pragma unroll
            for (int j = 0; j < 4; ++j) {
                aR[j] = *(const uint4*)(A + aRow + kt + 64 + j * 8);
                wR[j] = *(const uint4*)(W + wRow + kt + 64 + j * 8);
            }
        }
#pragma unroll
        for (int ks = 0; ks < 2; ++ks) {
            bf16x8 af[4], bfr[4];
#pragma unroll
            for (int i = 0; i < 4; ++i) {
                const int ra = wr + i * 16 + l15;
                af[i] = *(const bf16x8*)(AsB + ra * 128 + ((((ks << 2) + l4) ^ (ra & 7)) << 4));
                const int rb = wc + i * 16 + l15;
                bfr[i] = *(const bf16x8*)(BsB + rb * 128 + ((((ks << 2) + l4) ^ (rb & 7)) << 4));
            }
#pragma unroll
            for (int i = 0; i < 4; ++i)
#pragma unroll
                for (int j = 0; j < 4; ++j)
                    acc[i][j] = __builtin_amdgcn_mfma_f32_16x16x32_bf16(af[i], bfr[j], acc[i][j], 0, 0, 0);
        }
    }

    // ---- epilogue: LDS transpose -> vectorized stores ----
    // Per-wave scratch: 16 rows x 68 floats (pad 4 -> bank-shift per row).
    float* eps = (float*)smemU + (size_t)w * 1088;
    // bias for this lane's 4 consecutive columns n = n0+wc+l15*4 .. +3
    float4 bv4 = make_float4(0.f, 0.f, 0.f, 0.f);
    if (bias) {
        const int n = n0 + wc + l15 * 4;
        if (f) {
            bv4 = *(const float4*)((const float*)bias + bOff + n);
        } else {
            ushort4 bu = *(const ushort4*)((const u16*)bias + bOff + n);
            bv4 = make_float4(bf2f(bu.x), bf2f(bu.y), bf2f(bu.z), bf2f(bu.w));
        }
    }
#pragma unroll
    for (int i = 0; i < 4; ++i) {
        __syncthreads();    // As/Bs (or prior i scratch) fully consumed by all waves
        // scatter: eps[rr][cc] = value at (row_b = wr+i*16+rr, col_b = wc+cc)
#pragma unroll
        for (int j = 0; j < 4; ++j)
#pragma unroll
            for (int r = 0; r < 4; ++r)
                eps[(l4 * 4 + r) * 68 + j * 16 + l15] = acc[i][j][r];
        __syncthreads();    // emits lgkmcnt(0): writes visible before reads
#pragma unroll
        for (int c = 0; c < 4; ++c) {
            const int rr = l4 + 4 * c;
            float4 v4 = *(const float4*)&eps[rr * 68 + l15 * 4];
            v4.x += bv4.x; v4.y += bv4.y; v4.z += bv4.z; v4.w += bv4.w;
            const int m = m0 + wr + i * 16 + rr;
            const int n = n0 + wc + l15 * 4;
            if (res) {
                ushort4 r4 = *(const ushort4*)&res[(size_t)m * N + n];
                v4.x += bf2f(r4.x); v4.y += bf2f(r4.y);
                v4.z += bf2f(r4.z); v4.w += bf2f(r4.w);
            }
            if (outFlagged && f) {
                f32x4 nv = {v4.x, v4.y, v4.z, v4.w};
                __builtin_nontemporal_store(nv, (f32x4*)((float*)outP + (size_t)m * N + n));
            } else {
                u32x2 o;
                o.x = (unsigned)f2bf(v4.x) | ((unsigned)f2bf(v4.y) << 16);
                o.y = (unsigned)f2bf(v4.z) | ((unsigned)f2bf(v4.w) << 16);
                u32x2* dst = (u32x2*)((u16*)outP + (size_t)m * N + n);
                if (outFlagged) __builtin_nontemporal_store(o, dst);
                else            *dst = o;
            }
        }
    }
}

// ---------- 3. MFMA flash attention (unchanged from R5) ----------
__global__ __launch_bounds__(256) void flash_attn(const u16* __restrict__ q,
                                                  const u16* __restrict__ k,
                                                  const u16* __restrict__ v,
                                                  u16* __restrict__ ctx) {
    const int bh = blockIdx.x;          // 0..B*H-1
    const int b = bh >> 4;              // /HH
    const int hd = bh & 15;             // %HH
    const int qt = gridDim.y - 1 - blockIdx.y;  // heavy tiles first
    const int qb = qt * 64;
    const int tid = threadIdx.x;
    const int w = tid >> 6;             // wave 0..3
    const int lane = tid & 63;
    const int l15 = lane & 15;
    const int l4 = lane >> 4;           // 0..3
    const int qw = qb + w * 16;         // wave's first query row
    const float scale = 0.125f;         // 1/sqrt(64)

    __shared__ u16 KsS[32 * 64];        // 4KB
    __shared__ u16 VtS[64 * 32];        // 4KB (transposed V)
    __shared__ u16 PwS[4][16 * 32];     // 4KB (per-wave P)
    char* Ks = (char*)KsS;
    char* Vt = (char*)VtS;
    char* Pw = (char*)PwS[w];

    // Q fragments (A operand), held in registers for the whole block
    const size_t qoff = ((size_t)(b * TT + qw + l15)) * CC + hd * DD + l4 * 8;
    const bf16x8 qf0 = *(const bf16x8*)(q + qoff);        // d 0..31 chunk
    const bf16x8 qf1 = *(const bf16x8*)(q + qoff + 32);   // d 32..63 chunk

    f32x4 zero4 = {0.f, 0.f, 0.f, 0.f};
    f32x4 ctxa[4] = {zero4, zero4, zero4, zero4};         // ctx[16 q][64 d]
    float m[4]    = {-1e30f, -1e30f, -1e30f, -1e30f};     // running row max
    float lsum[4] = {0.f, 0.f, 0.f, 0.f};                 // per-lane partial denom

    // block-cooperative staging assignment: thread -> (key row, d-octet)
    const int skey = tid >> 3;          // 0..31
    const int sd8 = tid & 7;            // 0..7
    const int kWByte = skey * 128 + ((sd8 ^ (skey & 7)) << 4);      // swizzled K dest
    const int keyx2 = (skey ^ ((sd8 & 3) << 3)) * 2;                // swizzled Vt key

    const int nt = qt * 2 + 2;          // 32-key tiles covering [0, qb+64)

    uint4 kreg, vreg;                   // register double-buffer for staging
    {
        const size_t g = ((size_t)(b * TT + skey)) * CC + hd * DD + sd8 * 8;
        kreg = *(const uint4*)(k + g);
        vreg = *(const uint4*)(v + g);
    }

    for (int t = 0; t < nt; ++t) {
        const int kv0 = t * 32;
        // ---- write staged regs -> LDS ----
        *(uint4*)(Ks + kWByte) = kreg;
        {
            const u16* vr = (const u16*)&vreg;
#pragma unroll
            for (int j = 0; j < 8; ++j)     // Vt[d][key'] transpose-scatter
                *(u16*)(Vt + (sd8 * 8 + j) * 64 + keyx2) = vr[j];
        }
        __syncthreads();
        // ---- issue next tile's global loads (latency hides under compute) ----
        if (t + 1 < nt) {
            const size_t g = ((size_t)(b * TT + kv0 + 32 + skey)) * CC + hd * DD + sd8 * 8;
            kreg = *(const uint4*)(k + g);
            vreg = *(const uint4*)(v + g);
        }
        if (kv0 <= qw + 15) {   // wave-uniform: skip fully-masked tiles
            // ---- QK^T: S[16 q][32 key], 2 C-tiles x 2 K-chunks ----
            f32x4 s[2];
#pragma unroll
            for (int c = 0; c < 2; ++c) {
                const int key = c * 16 + l15;
                const int kb = key * 128;
                const int kx = key & 7;
                const bf16x8 kf0 = *(const bf16x8*)(Ks + kb + ((l4 ^ kx) << 4));
                const bf16x8 kf1 = *(const bf16x8*)(Ks + kb + (((4 + l4) ^ kx) << 4));
                f32x4 z = {0.f, 0.f, 0.f, 0.f};
                z = __builtin_amdgcn_mfma_f32_16x16x32_bf16(qf0, kf0, z, 0, 0, 0);
                z = __builtin_amdgcn_mfma_f32_16x16x32_bf16(qf1, kf1, z, 0, 0, 0);
                s[c] = z;
            }
            // ---- scale + causal mask (element: key <= row) ----
            float sv[2][4];
#pragma unroll
            for (int c = 0; c < 2; ++c) {
                const int key = kv0 + c * 16 + l15;
#pragma unroll
                for (int r = 0; r < 4; ++r) {
                    const int row = qw + l4 * 4 + r;
                    sv[c][r] = (key <= row) ? s[c][r] * scale : -1e30f;
                }
            }
            // ---- online softmax (row spread over 16 lanes; xor 1/2/4/8 stays in group) ----
#pragma unroll
            for (int r = 0; r < 4; ++r) {
                float mt = fmaxf(sv[0][r], sv[1][r]);
                mt = fmaxf(mt, __shfl_xor(mt, 1, 64));
                mt = fmaxf(mt, __shfl_xor(mt, 2, 64));
                mt = fmaxf(mt, __shfl_xor(mt, 4, 64));
                mt = fmaxf(mt, __shfl_xor(mt, 8, 64));
                const float mn = fmaxf(m[r], mt);
                const float corr = __expf(m[r] - mn);   // 0 on first tile (m=-1e30)
                m[r] = mn;
                const float p0 = __expf(sv[0][r] - mn); // masked -> exp(-1e30)=0
                const float p1 = __expf(sv[1][r] - mn);
                lsum[r] = lsum[r] * corr + p0 + p1;
#pragma unroll
                for (int nb = 0; nb < 4; ++nb) ctxa[nb][r] *= corr;
                const int rowb = (l4 * 4 + r) * 64;
                *(u16*)(Pw + rowb + l15 * 2) = f2bf(p0);
                *(u16*)(Pw + rowb + 32 + l15 * 2) = f2bf(p1);
            }
            // ---- PV: ctx += P[16x32] * V[32x64] ----
            const bf16x8 pf = *(const bf16x8*)(Pw + l15 * 64 + l4 * 16);  // A-frag
#pragma unroll
            for (int nb = 0; nb < 4; ++nb) {
                const int d = nb * 16 + l15;
                const bf16x8 vf = *(const bf16x8*)(Vt + d * 64 + ((l4 ^ ((d >> 3) & 3)) << 4));
                ctxa[nb] = __builtin_amdgcn_mfma_f32_16x16x32_bf16(pf, vf, ctxa[nb], 0, 0, 0);
            }
        }
        __syncthreads();
    }

    // ---- epilogue: reduce denominators across the 16 column lanes, write bf16 ----
    float inv[4];
#pragma unroll
    for (int r = 0; r < 4; ++r) {
        float sred = lsum[r];
        sred += __shfl_xor(sred, 1, 64);
        sred += __shfl_xor(sred, 2, 64);
        sred += __shfl_xor(sred, 4, 64);
        sred += __shfl_xor(sred, 8, 64);
        inv[r] = 1.0f / sred;   // >0: key 0 is always unmasked in tile 0
    }
    u16* cp = ctx + ((size_t)(b * TT + qw)) * CC + hd * DD;
#pragma unroll
    for (int r = 0; r < 4; ++r) {
        const size_t rb = (size_t)(l4 * 4 + r) * CC;
#pragma unroll
        for (int nb = 0; nb < 4; ++nb)
            cp[rb + nb * 16 + l15] = f2bf(ctxa[nb][r] * inv[r]);
    }
}

// ---------- 4. d2d copy (h -> scratch), 16B per thread ----------
__global__ __launch_bounds__(256) void copy16_kernel(const uint4* __restrict__ src,
                                                     uint4* __restrict__ dst) {
    const size_t i = (size_t)blockIdx.x * 256 + threadIdx.x;
    dst[i] = src[i];
}

// ---------- 5. loss: per-row logsumexp + NLL ----------
__global__ __launch_bounds__(256) void loss_row(const void* __restrict__ logits,
                                                const int* __restrict__ target,
                                                float* __restrict__ nll,
                                                const int* __restrict__ flagp) {
    const int f = *flagp;
    const int r = blockIdx.x;
    __shared__ float red[4];
    const float* lpf = (const float*)logits + (size_t)r * VV;
    const u16*   lpb = (const u16*)logits + (size_t)r * VV;

    float lmax = -1e30f;
    if (f) { for (int i = threadIdx.x; i < VV; i += 256) lmax = fmaxf(lmax, lpf[i]); }
    else   { for (int i = threadIdx.x; i < VV; i += 256) lmax = fmaxf(lmax, bf2f(lpb[i])); }
#pragma unroll
    for (int off = 32; off > 0; off >>= 1) lmax = fmaxf(lmax, __shfl_down(lmax, off, 64));
    const int wid = threadIdx.x >> 6, lid = threadIdx.x & 63;
    if (lid == 0) red[wid] = lmax;
    __syncthreads();
    lmax = fmaxf(fmaxf(red[0], red[1]), fmaxf(red[2], red[3]));

    float sum = 0.f;
    if (f) { for (int i = threadIdx.x; i < VV; i += 256) sum += __expf(lpf[i] - lmax); }
    else   { for (int i = threadIdx.x; i < VV; i += 256) sum += __expf(bf2f(lpb[i]) - lmax); }
#pragma unroll
    for (int off = 32; off > 0; off >>= 1) sum += __shfl_down(sum, off, 64);
    __syncthreads();
    if (lid == 0) red[wid] = sum;
    __syncthreads();
    if (threadIdx.x == 0) {
        const float s = red[0] + red[1] + red[2] + red[3];
        const float tl = f ? lpf[target[r]] : bf2f(lpb[target[r]]);
        nll[r] = lmax + __logf(s) - tl;   // = -(log_softmax at target)
    }
}

__global__ __launch_bounds__(256) void loss_final(const float* __restrict__ nll,
                                                  void* __restrict__ out,
                                                  const int* __restrict__ flagp) {
    __shared__ float red[4];
    float s = 0.f;
    for (int i = threadIdx.x; i < MM; i += 256) s += nll[i];
#pragma unroll
    for (int off = 32; off > 0; off >>= 1) s += __shfl_down(s, off, 64);
    if ((threadIdx.x & 63) == 0) red[threadIdx.x >> 6] = s;
    __syncthreads();
    if (threadIdx.x == 0) {
        const float t = (red[0] + red[1] + red[2] + red[3]) / (float)MM;
        if (*flagp) ((float*)out)[(size_t)MM * VV] = t;
        else        ((u16*)out)[(size_t)MM * VV] = f2bf(t);
    }
}

// ---------- launch ----------
extern "C" void kernel_launch(void* const* d_in, const int* in_sizes, int n_in,
                              void* d_out, int out_size, void* d_ws, size_t ws_size,
                              hipStream_t stream) {
    const int* x      = (const int*)d_in[0];
    const int* target = (const int*)d_in[1];
    const void* ew  = d_in[2];
    const void* pos = d_in[3];
    const void* Wq  = d_in[4];
    const void* bq  = d_in[5];
    const void* Wk  = d_in[6];
    const void* bk  = d_in[7];
    const void* Wv  = d_in[8];
    const void* bv  = d_in[9];
    const void* Wo  = d_in[10];
    const void* bo  = d_in[11];
    const void* Wu  = d_in[12];

    int* flagp = (int*)d_ws;   // 4 bytes of workspace: dtype flag

    // bf16 scratch inside d_out (dead until logits GEMM; >=64 MiB both modes):
    u16* outw = (u16*)d_out;
    u16* hB  = outw;                                  // [ 0M,  8M)
    u16* qB  = outw + (size_t)1 * MM * CC;            // [ 8M, 16M)
    u16* kB  = outw + (size_t)2 * MM * CC;            // [16M, 24M)
    u16* vB  = outw + (size_t)3 * MM * CC;            // [24M, 32M)
    u16* ctx = qB;  // flash block writes exactly the (row, head-slice) it read
    // bf16 projection weights in d_out [32M, 48M) (both modes; dead until
    // the logits GEMM, and all consumers run before it):
    const size_t WSZ = (size_t)LL * CC * CC;          // 2M elements = 4MB bf16
    u16* WqB = (u16*)((char*)d_out + (size_t)32 * 1024 * 1024);
    u16* WkB = WqB + WSZ;
    u16* WvB = WkB + WSZ;
    u16* WoB = WvB + WSZ;
    // Scratch inside the consumed embed_w buffer (fp32 mode: 32 MiB; bf16: 16 MiB):
    u16* hScr  = (u16*)ew;                                   // [ 0M,  8M)
    float* nll = (float*)((char*)ew + 12u * 1024 * 1024);    // [12M, 12M+16K)
    u16* WuB   = (u16*)((char*)ew + 16u * 1024 * 1024);      // [16M, 32M) fp32 mode ONLY

    probe_kernel<<<1, 256, 0, stream>>>((const u16*)Wu, flagp);
    embed_kernel<<<MM, 256, 0, stream>>>(x, ew, pos, hB, flagp);  // last read of ew table

    // weight conversion (after embed: WuB overlays the live embedding table)
    cvt_w<<<WSZ / 2048, 256, 0, stream>>>(Wq, WqB, 0, flagp);
    cvt_w<<<WSZ / 2048, 256, 0, stream>>>(Wk, WkB, 0, flagp);
    cvt_w<<<WSZ / 2048, 256, 0, stream>>>(Wv, WvB, 0, flagp);
    cvt_w<<<WSZ / 2048, 256, 0, stream>>>(Wo, WoB, 0, flagp);
    cvt_w<<<(size_t)VV * CC / 2048, 256, 0, stream>>>(Wu, WuB, 1, flagp);  // fp32 mode only

    const dim3 gP(CC / 128, MM / 128);   // projection GEMMs: 8 x 32 blocks
    for (int l = 0; l < LL; ++l) {
        const size_t wOffE = (size_t)l * CC * CC, bOff = (size_t)l * CC;
        gemm_bf16<<<gP, 256, 0, stream>>>(hB, WqB + wOffE, nullptr, qB, bq, bOff, nullptr, MM, CC, CC, 0, flagp);
        gemm_bf16<<<gP, 256, 0, stream>>>(hB, WkB + wOffE, nullptr, kB, bk, bOff, nullptr, MM, CC, CC, 0, flagp);
        gemm_bf16<<<gP, 256, 0, stream>>>(hB, WvB + wOffE, nullptr, vB, bv, bOff, nullptr, MM, CC, CC, 0, flagp);
        flash_attn<<<dim3(BB * HH, TT / 64), 256, 0, stream>>>(qB, kB, vB, ctx);
        // out-proj + residual, in-place into hB (res read/write at identical (m,n))
        gemm_bf16<<<gP, 256, 0, stream>>>(ctx, WoB + wOffE, nullptr, hB, bo, bOff, hB, MM, CC, CC, 0, flagp);
    }

    // move h out of d_out, then logits GEMM overwrites d_out (dtype per flag)
    copy16_kernel<<<(MM * CC * 2 / 16) / 256, 256, 0, stream>>>((const uint4*)hB, (uint4*)hScr);
    gemm_bf16<<<dim3(VV / 128, MM / 128), 256, 0, stream>>>(hScr, WuB, Wu, d_out,
                                                            nullptr, 0, nullptr, MM, VV, CC, 1, flagp);
    loss_row<<<MM, 256, 0, stream>>>(d_out, target, nll, flagp);
    loss_final<<<1, 256, 0, stream>>>(nll, d_out, flagp);
}

// Round 5
// 1176.527 us; speedup vs baseline: 1.0115x; 1.0115x over previous
//
#include <hip/hip_runtime.h>

// Problem constants (reference: B=2, T=2048, C=1024, V=8192, L=2, H=16, d=64)
#define BB 2
#define TT 2048
#define CC 1024
#define VV 8192
#define LL 2
#define HH 16
#define DD 64
#define MM (BB * TT) // 4096 rows

// R8: XCD-aware block swizzle (T1). R7b post-mortem: logits gemm is NOT
// store-bound (vectorized nt stores changed nothing); it is fetch-locality
// bound — MfmaUtil 8.3% = 68.7GF/331us exactly, VALU 3.5%, and 1.07 GB of
// logical A/W tile reads get ~zero per-XCD L2 reuse under default dispatch
// (panel-sharing blocks land on different XCDs) -> served from L3 at ~3TB/s.
// Fix: bijective remap so each XCD owns a column-stripe (W-stripe resident in
// its 4MB L2; A-panel reused by 8 consecutive blocks), m-major/n-inner.
// Same remap for flash_attn (XCD owns 4 heads -> 2MB K/V hot). Also: last
// out-proj writes hScr directly (res from hB), copy16 pass deleted.
using u16 = unsigned short;

typedef short bf16x8 __attribute__((ext_vector_type(8)));   // 8 bf16 = 4 VGPRs
typedef float f32x4 __attribute__((ext_vector_type(4)));    // MFMA accumulator
typedef unsigned int u32x2 __attribute__((ext_vector_type(2)));

__device__ __forceinline__ float bf2f(u16 u) {
    union { unsigned int i; float f; } x;
    x.i = ((unsigned int)u) << 16;
    return x.f;
}
__device__ __forceinline__ u16 f2bf(float f) {
    union { float f; unsigned int i; } x;
    x.f = f;
    unsigned int r = x.i + 0x7fffu + ((x.i >> 16) & 1u); // round-to-nearest-even
    return (u16)(r >> 16);
}

// ---------- 0. dtype probe (resolves fp32-vs-bf16 at runtime) ----------
__global__ __launch_bounds__(256) void probe_kernel(const u16* __restrict__ w,
                                                    int* __restrict__ flag) {
    __shared__ int cnt;
    if (threadIdx.x == 0) cnt = 0;
    __syncthreads();
    int c = 0;
    for (int i = threadIdx.x; i < 4096; i += 256) {
        const u16 u = w[2 * i];
        const int e = (u >> 7) & 0xff;
        if (e >= 125) ++c;
    }
    atomicAdd(&cnt, c);
    __syncthreads();
    if (threadIdx.x == 0) *flag = (cnt > 64) ? 1 : 0;
}

// ---------- 1. embedding + positional -> bf16 h ----------
__global__ __launch_bounds__(256) void embed_kernel(const int* __restrict__ x,
                                                    const void* __restrict__ ew,
                                                    const void* __restrict__ pos,
                                                    u16* __restrict__ h,
                                                    const int* __restrict__ flagp) {
    const int f = *flagp;
    const int i = blockIdx.x;        // token row 0..MM-1
    const int t = i & (TT - 1);      // position within sequence
    const int row = x[i];
    const int c = threadIdx.x * 4;
    float4 e, p;
    if (f) {
        e = *(const float4*)((const float*)ew + (size_t)row * CC + c);
        p = *(const float4*)((const float*)pos + (size_t)t * CC + c);
    } else {
        ushort4 eu = *(const ushort4*)((const u16*)ew + (size_t)row * CC + c);
        ushort4 pu = *(const ushort4*)((const u16*)pos + (size_t)t * CC + c);
        e = make_float4(bf2f(eu.x), bf2f(eu.y), bf2f(eu.z), bf2f(eu.w));
        p = make_float4(bf2f(pu.x), bf2f(pu.y), bf2f(pu.z), bf2f(pu.w));
    }
    ushort4 o;
    o.x = f2bf(e.x + p.x); o.y = f2bf(e.y + p.y);
    o.z = f2bf(e.z + p.z); o.w = f2bf(e.w + p.w);
    *(ushort4*)&h[(size_t)i * CC + c] = o;
}

// ---------- 1b. weight convert: fp32 -> bf16 (or bf16 copy) ----------
// onlyF=1: write only when flag==1 (dst scratch exists only in fp32 mode).
__global__ __launch_bounds__(256) void cvt_w(const void* __restrict__ src,
                                             u16* __restrict__ dst,
                                             int onlyF,
                                             const int* __restrict__ flagp) {
    const int f = *flagp;
    const size_t i = ((size_t)blockIdx.x * 256 + threadIdx.x) * 8;
    if (f) {
        const float* s = (const float*)src + i;
        float4 a = *(const float4*)s;
        float4 b = *(const float4*)(s + 4);
        uint4 o;
        o.x = (unsigned)f2bf(a.x) | ((unsigned)f2bf(a.y) << 16);
        o.y = (unsigned)f2bf(a.z) | ((unsigned)f2bf(a.w) << 16);
        o.z = (unsigned)f2bf(b.x) | ((unsigned)f2bf(b.y) << 16);
        o.w = (unsigned)f2bf(b.z) | ((unsigned)f2bf(b.w) << 16);
        *(uint4*)(dst + i) = o;
    } else if (!onlyF) {
        *(uint4*)(dst + i) = *(const uint4*)((const u16*)src + i);
    }
}

// ---------- 2. MFMA GEMM: out[m,n] = sum_k A[m,k]*W[n,k] (+bias[n]) (+res[m,n]) ----------
// A bf16 [M,K]; Wc bf16 [N,K] (converted scratch). If Walt!=null and flag==0,
// W = Walt (native bf16 weights, no scratch copy in bf16 mode).
// 128x128 tile, BK=64, 256 threads = 4 waves, each wave a 64x64 sub-tile
// (4x4 f32x4 accumulators). XOR-swizzled LDS (slot = octet ^ (row&7) on 128B
// rows) -> conflict-free ds_read/write_b128. XCD remap: gridDim.x%8==0;
// XCD x owns column-stripe of gx/8 n-blocks, iterated m-major/n-inner ->
// W-stripe resident in per-XCD L2, A-panel reused by consecutive blocks.
// Epilogue: acc transposed through per-wave padded LDS scratch (16x68 f32)
// so stores are dwordx4/x2 per lane; nontemporal for logits.
__global__ __launch_bounds__(256) void gemm_bf16(const u16* __restrict__ A,
                                                 const u16* __restrict__ Wc,
                                                 const void* __restrict__ Walt,
                                                 void* __restrict__ outP,
                                                 const void* __restrict__ bias, size_t bOff,
                                                 const u16* __restrict__ res,
                                                 int M, int N, int K, int outFlagged,
                                                 const int* __restrict__ flagp) {
    const int f = *flagp;
    const u16* W = (Walt && !f) ? (const u16*)Walt : Wc;

    __shared__ u16 smemU[2][128 * 64];   // 32 KB: As | Bs, reused by epilogue
    char* AsB = (char*)smemU[0];
    char* BsB = (char*)smemU[1];

    // ---- XCD-aware bijective remap (hardware round-robins wgid%8 -> XCD) ----
    const unsigned wgid = blockIdx.y * gridDim.x + blockIdx.x;
    const unsigned xcd = wgid & 7;
    const unsigned lix = wgid >> 3;
    const unsigned stripe = gridDim.x >> 3;        // n-blocks per XCD
    const unsigned nb = xcd * stripe + (lix % stripe);
    const unsigned mb = lix / stripe;
    const int m0 = mb * 128, n0 = nb * 128;

    const int tid = threadIdx.x;
    const int w = tid >> 6, lane = tid & 63, l15 = lane & 15, l4 = lane >> 4;
    const int wr = (w >> 1) * 64, wc = (w & 1) * 64;   // wave sub-tile origin

    // staging: thread -> row sr (0..127), octet group og = (tid&1)*4 .. +3
    const int sr = tid >> 1;
    const int og = (tid & 1) * 4;
    const size_t aRow = (size_t)(m0 + sr) * K + og * 8;
    const size_t wRow = (size_t)(n0 + sr) * K + og * 8;
    int dOff[4];
#pragma unroll
    for (int j = 0; j < 4; ++j)
        dOff[j] = sr * 128 + (((og + j) ^ (sr & 7)) << 4);

    f32x4 acc[4][4] = {};

    // prologue: load tile kt=0 into regs
    uint4 aR[4], wR[4];
#pragma unroll
    for (int j = 0; j < 4; ++j) {
        aR[j] = *(const uint4*)(A + aRow + j * 8);
        wR[j] = *(const uint4*)(W + wRow + j * 8);
    }

    for (int kt = 0; kt < K; kt += 64) {
        __syncthreads();            // previous tile fully consumed
#pragma unroll
        for (int j = 0; j < 4; ++j) *(uint4*)(AsB + dOff[j]) = aR[j];
#pragma unroll
        for (int j = 0; j < 4; ++j) *(uint4*)(BsB + dOff[j]) = wR[j];
        __syncthreads();
        if (kt + 64 < K) {          // issue next-tile loads; hide under MFMA
#pragma unroll
            for (int j = 0; j < 4; ++j) {
                aR[j] = *(const uint4*)(A + aRow + kt + 64 + j * 8);
                wR[j] = *(const uint4*)(W + wRow + kt + 64 + j * 8);
            }
        }
#pragma unroll
        for (int ks = 0; ks < 2; ++ks) {
            bf16x8 af[4], bfr[4];
#pragma unroll
            for (int i = 0; i < 4; ++i) {
                const int ra = wr + i * 16 + l15;
                af[i] = *(const bf16x8*)(AsB + ra * 128 + ((((ks << 2) + l4) ^ (ra & 7)) << 4));
                const int rb = wc + i * 16 + l15;
                bfr[i] = *(const bf16x8*)(BsB + rb * 128 + ((((ks << 2) + l4) ^ (rb & 7)) << 4));
            }
#pragma unroll
            for (int i = 0; i < 4; ++i)
#pragma unroll
                for (int j = 0; j < 4; ++j)
                    acc[i][j] = __builtin_amdgcn_mfma_f32_16x16x32_bf16(af[i], bfr[j], acc[i][j], 0, 0, 0);
        }
    }

    // ---- epilogue: LDS transpose -> vectorized stores ----
    // Per-wave scratch: 16 rows x 68 floats (pad 4 -> bank-shift per row).
    float* eps = (float*)smemU + (size_t)w * 1088;
    // bias for this lane's 4 consecutive columns n = n0+wc+l15*4 .. +3
    float4 bv4 = make_float4(0.f, 0.f, 0.f, 0.f);
    if (bias) {
        const int n = n0 + wc + l15 * 4;
        if (f) {
            bv4 = *(const float4*)((const float*)bias + bOff + n);
        } else {
            ushort4 bu = *(const ushort4*)((const u16*)bias + bOff + n);
            bv4 = make_float4(bf2f(bu.x), bf2f(bu.y), bf2f(bu.z), bf2f(bu.w));
        }
    }
#pragma unroll
    for (int i = 0; i < 4; ++i) {
        __syncthreads();    // As/Bs (or prior i scratch) fully consumed by all waves
        // scatter: eps[rr][cc] = value at (row_b = wr+i*16+rr, col_b = wc+cc)
#pragma unroll
        for (int j = 0; j < 4; ++j)
#pragma unroll
            for (int r = 0; r < 4; ++r)
                eps[(l4 * 4 + r) * 68 + j * 16 + l15] = acc[i][j][r];
        __syncthreads();    // emits lgkmcnt(0): writes visible before reads
#pragma unroll
        for (int c = 0; c < 4; ++c) {
            const int rr = l4 + 4 * c;
            float4 v4 = *(const float4*)&eps[rr * 68 + l15 * 4];
            v4.x += bv4.x; v4.y += bv4.y; v4.z += bv4.z; v4.w += bv4.w;
            const int m = m0 + wr + i * 16 + rr;
            const int n = n0 + wc + l15 * 4;
            if (res) {
                ushort4 r4 = *(const ushort4*)&res[(size_t)m * N + n];
                v4.x += bf2f(r4.x); v4.y += bf2f(r4.y);
                v4.z += bf2f(r4.z); v4.w += bf2f(r4.w);
            }
            if (outFlagged && f) {
                f32x4 nv = {v4.x, v4.y, v4.z, v4.w};
                __builtin_nontemporal_store(nv, (f32x4*)((float*)outP + (size_t)m * N + n));
            } else {
                u32x2 o;
                o.x = (unsigned)f2bf(v4.x) | ((unsigned)f2bf(v4.y) << 16);
                o.y = (unsigned)f2bf(v4.z) | ((unsigned)f2bf(v4.w) << 16);
                u32x2* dst = (u32x2*)((u16*)outP + (size_t)m * N + n);
                if (outFlagged) __builtin_nontemporal_store(o, dst);
                else            *dst = o;
            }
        }
    }
}

// ---------- 3. MFMA flash attention ----------
// XCD remap: XCD x owns head-stripe of 4 bh values -> its K/V hot set is
// 4 x 512KB = 2MB, resident in the per-XCD L2; q-tiles iterate heavy-first.
__global__ __launch_bounds__(256) void flash_attn(const u16* __restrict__ q,
                                                  const u16* __restrict__ k,
                                                  const u16* __restrict__ v,
                                                  u16* __restrict__ ctx) {
    const unsigned wgid = blockIdx.y * gridDim.x + blockIdx.x;
    const unsigned xcd = wgid & 7;
    const unsigned lix = wgid >> 3;
    const unsigned stripe = gridDim.x >> 3;          // bh per XCD (=4)
    const int bh = xcd * stripe + (lix % stripe);    // 0..B*H-1
    const int qt = gridDim.y - 1 - (lix / stripe);   // heavy q-tiles first
    const int b = bh >> 4;              // /HH
    const int hd = bh & 15;             // %HH
    const int qb = qt * 64;
    const int tid = threadIdx.x;
    const int w = tid >> 6;             // wave 0..3
    const int lane = tid & 63;
    const int l15 = lane & 15;
    const int l4 = lane >> 4;           // 0..3
    const int qw = qb + w * 16;         // wave's first query row
    const float scale = 0.125f;         // 1/sqrt(64)

    __shared__ u16 KsS[32 * 64];        // 4KB
    __shared__ u16 VtS[64 * 32];        // 4KB (transposed V)
    __shared__ u16 PwS[4][16 * 32];     // 4KB (per-wave P)
    char* Ks = (char*)KsS;
    char* Vt = (char*)VtS;
    char* Pw = (char*)PwS[w];

    // Q fragments (A operand), held in registers for the whole block
    const size_t qoff = ((size_t)(b * TT + qw + l15)) * CC + hd * DD + l4 * 8;
    const bf16x8 qf0 = *(const bf16x8*)(q + qoff);        // d 0..31 chunk
    const bf16x8 qf1 = *(const bf16x8*)(q + qoff + 32);   // d 32..63 chunk

    f32x4 zero4 = {0.f, 0.f, 0.f, 0.f};
    f32x4 ctxa[4] = {zero4, zero4, zero4, zero4};         // ctx[16 q][64 d]
    float m[4]    = {-1e30f, -1e30f, -1e30f, -1e30f};     // running row max
    float lsum[4] = {0.f, 0.f, 0.f, 0.f};                 // per-lane partial denom

    // block-cooperative staging assignment: thread -> (key row, d-octet)
    const int skey = tid >> 3;          // 0..31
    const int sd8 = tid & 7;            // 0..7
    const int kWByte = skey * 128 + ((sd8 ^ (skey & 7)) << 4);      // swizzled K dest
    const int keyx2 = (skey ^ ((sd8 & 3) << 3)) * 2;                // swizzled Vt key

    const int nt = qt * 2 + 2;          // 32-key tiles covering [0, qb+64)

    uint4 kreg, vreg;                   // register double-buffer for staging
    {
        const size_t g = ((size_t)(b * TT + skey)) * CC + hd * DD + sd8 * 8;
        kreg = *(const uint4*)(k + g);
        vreg = *(const uint4*)(v + g);
    }

    for (int t = 0; t < nt; ++t) {
        const int kv0 = t * 32;
        // ---- write staged regs -> LDS ----
        *(uint4*)(Ks + kWByte) = kreg;
        {
            const u16* vr = (const u16*)&vreg;
#pragma unroll
            for (int j = 0; j < 8; ++j)     // Vt[d][key'] transpose-scatter
                *(u16*)(Vt + (sd8 * 8 + j) * 64 + keyx2) = vr[j];
        }
        __syncthreads();
        // ---- issue next tile's global loads (latency hides under compute) ----
        if (t + 1 < nt) {
            const size_t g = ((size_t)(b * TT + kv0 + 32 + skey)) * CC + hd * DD + sd8 * 8;
            kreg = *(const uint4*)(k + g);
            vreg = *(const uint4*)(v + g);
        }
        if (kv0 <= qw + 15) {   // wave-uniform: skip fully-masked tiles
            // ---- QK^T: S[16 q][32 key], 2 C-tiles x 2 K-chunks ----
            f32x4 s[2];
#pragma unroll
            for (int c = 0; c < 2; ++c) {
                const int key = c * 16 + l15;
                const int kb = key * 128;
                const int kx = key & 7;
                const bf16x8 kf0 = *(const bf16x8*)(Ks + kb + ((l4 ^ kx) << 4));
                const bf16x8 kf1 = *(const bf16x8*)(Ks + kb + (((4 + l4) ^ kx) << 4));
                f32x4 z = {0.f, 0.f, 0.f, 0.f};
                z = __builtin_amdgcn_mfma_f32_16x16x32_bf16(qf0, kf0, z, 0, 0, 0);
                z = __builtin_amdgcn_mfma_f32_16x16x32_bf16(qf1, kf1, z, 0, 0, 0);
                s[c] = z;
            }
            // ---- scale + causal mask (element: key <= row) ----
            float sv[2][4];
#pragma unroll
            for (int c = 0; c < 2; ++c) {
                const int key = kv0 + c * 16 + l15;
#pragma unroll
                for (int r = 0; r < 4; ++r) {
                    const int row = qw + l4 * 4 + r;
                    sv[c][r] = (key <= row) ? s[c][r] * scale : -1e30f;
                }
            }
            // ---- online softmax (row spread over 16 lanes; xor 1/2/4/8 stays in group) ----
#pragma unroll
            for (int r = 0; r < 4; ++r) {
                float mt = fmaxf(sv[0][r], sv[1][r]);
                mt = fmaxf(mt, __shfl_xor(mt, 1, 64));
                mt = fmaxf(mt, __shfl_xor(mt, 2, 64));
                mt = fmaxf(mt, __shfl_xor(mt, 4, 64));
                mt = fmaxf(mt, __shfl_xor(mt, 8, 64));
                const float mn = fmaxf(m[r], mt);
                const float corr = __expf(m[r] - mn);   // 0 on first tile (m=-1e30)
                m[r] = mn;
                const float p0 = __expf(sv[0][r] - mn); // masked -> exp(-1e30)=0
                const float p1 = __expf(sv[1][r] - mn);
                lsum[r] = lsum[r] * corr + p0 + p1;
#pragma unroll
                for (int nb = 0; nb < 4; ++nb) ctxa[nb][r] *= corr;
                const int rowb = (l4 * 4 + r) * 64;
                *(u16*)(Pw + rowb + l15 * 2) = f2bf(p0);
                *(u16*)(Pw + rowb + 32 + l15 * 2) = f2bf(p1);
            }
            // ---- PV: ctx += P[16x32] * V[32x64] ----
            const bf16x8 pf = *(const bf16x8*)(Pw + l15 * 64 + l4 * 16);  // A-frag
#pragma unroll
            for (int nb = 0; nb < 4; ++nb) {
                const int d = nb * 16 + l15;
                const bf16x8 vf = *(const bf16x8*)(Vt + d * 64 + ((l4 ^ ((d >> 3) & 3)) << 4));
                ctxa[nb] = __builtin_amdgcn_mfma_f32_16x16x32_bf16(pf, vf, ctxa[nb], 0, 0, 0);
            }
        }
        __syncthreads();
    }

    // ---- epilogue: reduce denominators across the 16 column lanes, write bf16 ----
    float inv[4];
#pragma unroll
    for (int r = 0; r < 4; ++r) {
        float sred = lsum[r];
        sred += __shfl_xor(sred, 1, 64);
        sred += __shfl_xor(sred, 2, 64);
        sred += __shfl_xor(sred, 4, 64);
        sred += __shfl_xor(sred, 8, 64);
        inv[r] = 1.0f / sred;   // >0: key 0 is always unmasked in tile 0
    }
    u16* cp = ctx + ((size_t)(b * TT + qw)) * CC + hd * DD;
#pragma unroll
    for (int r = 0; r < 4; ++r) {
        const size_t rb = (size_t)(l4 * 4 + r) * CC;
#pragma unroll
        for (int nb = 0; nb < 4; ++nb)
            cp[rb + nb * 16 + l15] = f2bf(ctxa[nb][r] * inv[r]);
    }
}

// ---------- 5. loss: per-row logsumexp + NLL ----------
__global__ __launch_bounds__(256) void loss_row(const void* __restrict__ logits,
                                                const int* __restrict__ target,
                                                float* __restrict__ nll,
                                                const int* __restrict__ flagp) {
    const int f = *flagp;
    const int r = blockIdx.x;
    __shared__ float red[4];
    const float* lpf = (const float*)logits + (size_t)r * VV;
    const u16*   lpb = (const u16*)logits + (size_t)r * VV;

    float lmax = -1e30f;
    if (f) { for (int i = threadIdx.x; i < VV; i += 256) lmax = fmaxf(lmax, lpf[i]); }
    else   { for (int i = threadIdx.x; i < VV; i += 256) lmax = fmaxf(lmax, bf2f(lpb[i])); }
#pragma unroll
    for (int off = 32; off > 0; off >>= 1) lmax = fmaxf(lmax, __shfl_down(lmax, off, 64));
    const int wid = threadIdx.x >> 6, lid = threadIdx.x & 63;
    if (lid == 0) red[wid] = lmax;
    __syncthreads();
    lmax = fmaxf(fmaxf(red[0], red[1]), fmaxf(red[2], red[3]));

    float sum = 0.f;
    if (f) { for (int i = threadIdx.x; i < VV; i += 256) sum += __expf(lpf[i] - lmax); }
    else   { for (int i = threadIdx.x; i < VV; i += 256) sum += __expf(bf2f(lpb[i]) - lmax); }
#pragma unroll
    for (int off = 32; off > 0; off >>= 1) sum += __shfl_down(sum, off, 64);
    __syncthreads();
    if (lid == 0) red[wid] = sum;
    __syncthreads();
    if (threadIdx.x == 0) {
        const float s = red[0] + red[1] + red[2] + red[3];
        const float tl = f ? lpf[target[r]] : bf2f(lpb[target[r]]);
        nll[r] = lmax + __logf(s) - tl;   // = -(log_softmax at target)
    }
}

__global__ __launch_bounds__(256) void loss_final(const float* __restrict__ nll,
                                                  void* __restrict__ out,
                                                  const int* __restrict__ flagp) {
    __shared__ float red[4];
    float s = 0.f;
    for (int i = threadIdx.x; i < MM; i += 256) s += nll[i];
#pragma unroll
    for (int off = 32; off > 0; off >>= 1) s += __shfl_down(s, off, 64);
    if ((threadIdx.x & 63) == 0) red[threadIdx.x >> 6] = s;
    __syncthreads();
    if (threadIdx.x == 0) {
        const float t = (red[0] + red[1] + red[2] + red[3]) / (float)MM;
        if (*flagp) ((float*)out)[(size_t)MM * VV] = t;
        else        ((u16*)out)[(size_t)MM * VV] = f2bf(t);
    }
}

// ---------- launch ----------
extern "C" void kernel_launch(void* const* d_in, const int* in_sizes, int n_in,
                              void* d_out, int out_size, void* d_ws, size_t ws_size,
                              hipStream_t stream) {
    const int* x      = (const int*)d_in[0];
    const int* target = (const int*)d_in[1];
    const void* ew  = d_in[2];
    const void* pos = d_in[3];
    const void* Wq  = d_in[4];
    const void* bq  = d_in[5];
    const void* Wk  = d_in[6];
    const void* bk  = d_in[7];
    const void* Wv  = d_in[8];
    const void* bv  = d_in[9];
    const void* Wo  = d_in[10];
    const void* bo  = d_in[11];
    const void* Wu  = d_in[12];

    int* flagp = (int*)d_ws;   // 4 bytes of workspace: dtype flag

    // bf16 scratch inside d_out (dead until logits GEMM; >=64 MiB both modes):
    u16* outw = (u16*)d_out;
    u16* hB  = outw;                                  // [ 0M,  8M)
    u16* qB  = outw + (size_t)1 * MM * CC;            // [ 8M, 16M)
    u16* kB  = outw + (size_t)2 * MM * CC;            // [16M, 24M)
    u16* vB  = outw + (size_t)3 * MM * CC;            // [24M, 32M)
    u16* ctx = qB;  // flash block writes exactly the (row, head-slice) it read
    // bf16 projection weights in d_out [32M, 48M) (both modes; dead until
    // the logits GEMM, and all consumers run before it):
    const size_t WSZ = (size_t)LL * CC * CC;          // 2M elements = 4MB bf16
    u16* WqB = (u16*)((char*)d_out + (size_t)32 * 1024 * 1024);
    u16* WkB = WqB + WSZ;
    u16* WvB = WkB + WSZ;
    u16* WoB = WvB + WSZ;
    // Scratch inside the consumed embed_w buffer (fp32 mode: 32 MiB; bf16: 16 MiB):
    u16* hScr  = (u16*)ew;                                   // [ 0M,  8M)
    float* nll = (float*)((char*)ew + 12u * 1024 * 1024);    // [12M, 12M+16K)
    u16* WuB   = (u16*)((char*)ew + 16u * 1024 * 1024);      // [16M, 32M) fp32 mode ONLY

    probe_kernel<<<1, 256, 0, stream>>>((const u16*)Wu, flagp);
    embed_kernel<<<MM, 256, 0, stream>>>(x, ew, pos, hB, flagp);  // last read of ew table

    // weight conversion (after embed: WuB overlays the live embedding table)
    cvt_w<<<WSZ / 2048, 256, 0, stream>>>(Wq, WqB, 0, flagp);
    cvt_w<<<WSZ / 2048, 256, 0, stream>>>(Wk, WkB, 0, flagp);
    cvt_w<<<WSZ / 2048, 256, 0, stream>>>(Wv, WvB, 0, flagp);
    cvt_w<<<WSZ / 2048, 256, 0, stream>>>(Wo, WoB, 0, flagp);
    cvt_w<<<(size_t)VV * CC / 2048, 256, 0, stream>>>(Wu, WuB, 1, flagp);  // fp32 mode only

    const dim3 gP(CC / 128, MM / 128);   // projection GEMMs: 8 x 32 blocks
    for (int l = 0; l < LL; ++l) {
        const size_t wOffE = (size_t)l * CC * CC, bOff = (size_t)l * CC;
        gemm_bf16<<<gP, 256, 0, stream>>>(hB, WqB + wOffE, nullptr, qB, bq, bOff, nullptr, MM, CC, CC, 0, flagp);
        gemm_bf16<<<gP, 256, 0, stream>>>(hB, WkB + wOffE, nullptr, kB, bk, bOff, nullptr, MM, CC, CC, 0, flagp);
        gemm_bf16<<<gP, 256, 0, stream>>>(hB, WvB + wOffE, nullptr, vB, bv, bOff, nullptr, MM, CC, CC, 0, flagp);
        flash_attn<<<dim3(BB * HH, TT / 64), 256, 0, stream>>>(qB, kB, vB, ctx);
        // out-proj + residual; last layer writes hScr directly (res from hB)
        u16* outH = (l == LL - 1) ? hScr : hB;
        gemm_bf16<<<gP, 256, 0, stream>>>(ctx, WoB + wOffE, nullptr, outH, bo, bOff, hB, MM, CC, CC, 0, flagp);
    }

    // logits GEMM overwrites d_out (dtype per flag); h already lives in hScr
    gemm_bf16<<<dim3(VV / 128, MM / 128), 256, 0, stream>>>(hScr, WuB, Wu, d_out,
                                                            nullptr, 0, nullptr, MM, VV, CC, 1, flagp);
    loss_row<<<MM, 256, 0, stream>>>(d_out, target, nll, flagp);
    loss_final<<<1, 256, 0, stream>>>(nll, d_out, flagp);
}

// Round 7
// 749.609 us; speedup vs baseline: 1.5876x; 1.5695x over previous
//
#include <hip/hip_runtime.h>

// Problem constants (reference: B=2, T=2048, C=1024, V=8192, L=2, H=16, d=64)
#define BB 2
#define TT 2048
#define CC 1024
#define VV 8192
#define LL 2
#define HH 16
#define DD 64
#define MM (BB * TT) // 4096 rows

// R10 = R9 resubmit (container infra failure, no measurement). Theory stands:
// gemm K-loop -> global_load_lds (m97 structure). R7b/R8 post-mortem: dur
// invariant across store-vectorization AND XCD swizzle; MfmaUtil 8.4%, VALU
// 3.5%, occ 43% -> global-load LATENCY exposure in the reg-staged loop.
// Fix: direct-to-LDS staging (no reg round-trip, no ds_write phase): single
// 32KB linear LDS buffer, 2 barriers/step, BK=64. Rule #21: linear LDS dest
// (HW: base+lane*16) + pre-swizzled GLOBAL source (slot = octet^((row>>1)&7))
// + same XOR on fragment ds_read_b128 -> uniform bank spread, LDS BW floor.
using u16 = unsigned short;

typedef short bf16x8 __attribute__((ext_vector_type(8)));   // 8 bf16 = 4 VGPRs
typedef float f32x4 __attribute__((ext_vector_type(4)));    // MFMA accumulator
typedef unsigned int u32x2 __attribute__((ext_vector_type(2)));

__device__ __forceinline__ float bf2f(u16 u) {
    union { unsigned int i; float f; } x;
    x.i = ((unsigned int)u) << 16;
    return x.f;
}
__device__ __forceinline__ u16 f2bf(float f) {
    union { float f; unsigned int i; } x;
    x.f = f;
    unsigned int r = x.i + 0x7fffu + ((x.i >> 16) & 1u); // round-to-nearest-even
    return (u16)(r >> 16);
}

// ---------- 0. dtype probe (resolves fp32-vs-bf16 at runtime) ----------
__global__ __launch_bounds__(256) void probe_kernel(const u16* __restrict__ w,
                                                    int* __restrict__ flag) {
    __shared__ int cnt;
    if (threadIdx.x == 0) cnt = 0;
    __syncthreads();
    int c = 0;
    for (int i = threadIdx.x; i < 4096; i += 256) {
        const u16 u = w[2 * i];
        const int e = (u >> 7) & 0xff;
        if (e >= 125) ++c;
    }
    atomicAdd(&cnt, c);
    __syncthreads();
    if (threadIdx.x == 0) *flag = (cnt > 64) ? 1 : 0;
}

// ---------- 1. embedding + positional -> bf16 h ----------
__global__ __launch_bounds__(256) void embed_kernel(const int* __restrict__ x,
                                                    const void* __restrict__ ew,
                                                    const void* __restrict__ pos,
                                                    u16* __restrict__ h,
                                                    const int* __restrict__ flagp) {
    const int f = *flagp;
    const int i = blockIdx.x;        // token row 0..MM-1
    const int t = i & (TT - 1);      // position within sequence
    const int row = x[i];
    const int c = threadIdx.x * 4;
    float4 e, p;
    if (f) {
        e = *(const float4*)((const float*)ew + (size_t)row * CC + c);
        p = *(const float4*)((const float*)pos + (size_t)t * CC + c);
    } else {
        ushort4 eu = *(const ushort4*)((const u16*)ew + (size_t)row * CC + c);
        ushort4 pu = *(const ushort4*)((const u16*)pos + (size_t)t * CC + c);
        e = make_float4(bf2f(eu.x), bf2f(eu.y), bf2f(eu.z), bf2f(eu.w));
        p = make_float4(bf2f(pu.x), bf2f(pu.y), bf2f(pu.z), bf2f(pu.w));
    }
    ushort4 o;
    o.x = f2bf(e.x + p.x); o.y = f2bf(e.y + p.y);
    o.z = f2bf(e.z + p.z); o.w = f2bf(e.w + p.w);
    *(ushort4*)&h[(size_t)i * CC + c] = o;
}

// ---------- 1b. weight convert: fp32 -> bf16 (or bf16 copy) ----------
// onlyF=1: write only when flag==1 (dst scratch exists only in fp32 mode).
__global__ __launch_bounds__(256) void cvt_w(const void* __restrict__ src,
                                             u16* __restrict__ dst,
                                             int onlyF,
                                             const int* __restrict__ flagp) {
    const int f = *flagp;
    const size_t i = ((size_t)blockIdx.x * 256 + threadIdx.x) * 8;
    if (f) {
        const float* s = (const float*)src + i;
        float4 a = *(const float4*)s;
        float4 b = *(const float4*)(s + 4);
        uint4 o;
        o.x = (unsigned)f2bf(a.x) | ((unsigned)f2bf(a.y) << 16);
        o.y = (unsigned)f2bf(a.z) | ((unsigned)f2bf(a.w) << 16);
        o.z = (unsigned)f2bf(b.x) | ((unsigned)f2bf(b.y) << 16);
        o.w = (unsigned)f2bf(b.z) | ((unsigned)f2bf(b.w) << 16);
        *(uint4*)(dst + i) = o;
    } else if (!onlyF) {
        *(uint4*)(dst + i) = *(const uint4*)((const u16*)src + i);
    }
}

// ---------- 2. MFMA GEMM: out[m,n] = sum_k A[m,k]*W[n,k] (+bias[n]) (+res[m,n]) ----------
// A bf16 [M,K]; Wc bf16 [N,K]. Walt used when flag==0 (native bf16 weights).
// 128x128 tile, BK=64, 256 threads = 4 waves, each a 64x64 sub-tile (4x4
// f32x4 acc). Staging: global_load_lds width=16 into LINEAR LDS rows (128B);
// per K-step each wave issues 8 loads (As rows [w*32,w*32+32) in 8-row
// chunks + same for Bs). Source octet pre-swizzled: so = o ^ ((row>>1)&7);
// fragment ds_read_b128 applies the same XOR -> uniform bank spread.
// K-loop: [barrier: buffer free][issue 8 gload_lds][barrier: vmcnt drain]
// [2x(8 ds_read + 16 MFMA)]. Epilogue: LDS-transpose -> dwordx4/x2 stores.
__global__ __launch_bounds__(256) void gemm_bf16(const u16* __restrict__ A,
                                                 const u16* __restrict__ Wc,
                                                 const void* __restrict__ Walt,
                                                 void* __restrict__ outP,
                                                 const void* __restrict__ bias, size_t bOff,
                                                 const u16* __restrict__ res,
                                                 int M, int N, int K, int outFlagged,
                                                 const int* __restrict__ flagp) {
    const int f = *flagp;
    const u16* W = (Walt && !f) ? (const u16*)Walt : Wc;

    __shared__ u16 smemU[2][128 * 64];   // 32 KB: As | Bs (linear), epilogue reuse
    u16* As = smemU[0];
    u16* Bs = smemU[1];
    char* AsB = (char*)As;
    char* BsB = (char*)Bs;

    // ---- XCD-aware bijective remap (neutral so far; keep for BW phase) ----
    const unsigned wgid = blockIdx.y * gridDim.x + blockIdx.x;
    const unsigned xcd = wgid & 7;
    const unsigned lix = wgid >> 3;
    const unsigned stripe = gridDim.x >> 3;        // n-blocks per XCD
    const unsigned nb = xcd * stripe + (lix % stripe);
    const unsigned mb = lix / stripe;
    const int m0 = mb * 128, n0 = nb * 128;

    const int tid = threadIdx.x;
    const int w = tid >> 6, lane = tid & 63, l15 = lane & 15, l4 = lane >> 4;
    const int wr = (w >> 1) * 64, wc = (w & 1) * 64;   // wave sub-tile origin

    // staging addresses: instr c stages tile rows [w*32+c*8, +8);
    // lane -> row r = r0 + (lane>>3), dest octet d = lane&7 (linear),
    // source octet so = d ^ ((r>>1)&7)  (inverse of the read-side XOR).
    size_t aBase[4], wBase[4];
    int ldsOff[4];
#pragma unroll
    for (int c = 0; c < 4; ++c) {
        const int r = w * 32 + c * 8 + (lane >> 3);
        const int so = (lane & 7) ^ ((r >> 1) & 7);
        aBase[c] = (size_t)(m0 + r) * K + so * 8;
        wBase[c] = (size_t)(n0 + r) * K + so * 8;
        ldsOff[c] = (w * 32 + c * 8) * 64;   // u16 elements (row*64)
    }

    f32x4 acc[4][4] = {};

    for (int kt = 0; kt < K; kt += 64) {
        __syncthreads();            // previous tile fully consumed
#pragma unroll
        for (int c = 0; c < 4; ++c) {
            __builtin_amdgcn_global_load_lds((const uint4*)(A + aBase[c] + kt),
                                             (uint4*)(As + ldsOff[c]), 16, 0, 0);
            __builtin_amdgcn_global_load_lds((const uint4*)(W + wBase[c] + kt),
                                             (uint4*)(Bs + ldsOff[c]), 16, 0, 0);
        }
        __syncthreads();            // compiler drains vmcnt before barrier
#pragma unroll
        for (int ks = 0; ks < 2; ++ks) {
            bf16x8 af[4], bfr[4];
#pragma unroll
            for (int i = 0; i < 4; ++i) {
                const int ra = wr + i * 16 + l15;
                af[i] = *(const bf16x8*)(AsB + ra * 128 + ((((ks << 2) + l4) ^ ((ra >> 1) & 7)) << 4));
                const int rb = wc + i * 16 + l15;
                bfr[i] = *(const bf16x8*)(BsB + rb * 128 + ((((ks << 2) + l4) ^ ((rb >> 1) & 7)) << 4));
            }
#pragma unroll
            for (int i = 0; i < 4; ++i)
#pragma unroll
                for (int j = 0; j < 4; ++j)
                    acc[i][j] = __builtin_amdgcn_mfma_f32_16x16x32_bf16(af[i], bfr[j], acc[i][j], 0, 0, 0);
        }
    }

    // ---- epilogue: LDS transpose -> vectorized stores ----
    // Per-wave scratch: 16 rows x 68 floats (pad 4 -> bank-shift per row).
    float* eps = (float*)smemU + (size_t)w * 1088;
    // bias for this lane's 4 consecutive columns n = n0+wc+l15*4 .. +3
    float4 bv4 = make_float4(0.f, 0.f, 0.f, 0.f);
    if (bias) {
        const int n = n0 + wc + l15 * 4;
        if (f) {
            bv4 = *(const float4*)((const float*)bias + bOff + n);
        } else {
            ushort4 bu = *(const ushort4*)((const u16*)bias + bOff + n);
            bv4 = make_float4(bf2f(bu.x), bf2f(bu.y), bf2f(bu.z), bf2f(bu.w));
        }
    }
#pragma unroll
    for (int i = 0; i < 4; ++i) {
        __syncthreads();    // As/Bs (or prior i scratch) fully consumed by all waves
        // scatter: eps[rr][cc] = value at (row_b = wr+i*16+rr, col_b = wc+cc)
#pragma unroll
        for (int j = 0; j < 4; ++j)
#pragma unroll
            for (int r = 0; r < 4; ++r)
                eps[(l4 * 4 + r) * 68 + j * 16 + l15] = acc[i][j][r];
        __syncthreads();    // emits lgkmcnt(0): writes visible before reads
#pragma unroll
        for (int c = 0; c < 4; ++c) {
            const int rr = l4 + 4 * c;
            float4 v4 = *(const float4*)&eps[rr * 68 + l15 * 4];
            v4.x += bv4.x; v4.y += bv4.y; v4.z += bv4.z; v4.w += bv4.w;
            const int m = m0 + wr + i * 16 + rr;
            const int n = n0 + wc + l15 * 4;
            if (res) {
                ushort4 r4 = *(const ushort4*)&res[(size_t)m * N + n];
                v4.x += bf2f(r4.x); v4.y += bf2f(r4.y);
                v4.z += bf2f(r4.z); v4.w += bf2f(r4.w);
            }
            if (outFlagged && f) {
                f32x4 nv = {v4.x, v4.y, v4.z, v4.w};
                __builtin_nontemporal_store(nv, (f32x4*)((float*)outP + (size_t)m * N + n));
            } else {
                u32x2 o;
                o.x = (unsigned)f2bf(v4.x) | ((unsigned)f2bf(v4.y) << 16);
                o.y = (unsigned)f2bf(v4.z) | ((unsigned)f2bf(v4.w) << 16);
                u32x2* dst = (u32x2*)((u16*)outP + (size_t)m * N + n);
                if (outFlagged) __builtin_nontemporal_store(o, dst);
                else            *dst = o;
            }
        }
    }
}

// ---------- 3. MFMA flash attention ----------
// XCD remap: XCD x owns head-stripe of 4 bh values -> its K/V hot set is
// 4 x 512KB = 2MB, resident in the per-XCD L2; q-tiles iterate heavy-first.
__global__ __launch_bounds__(256) void flash_attn(const u16* __restrict__ q,
                                                  const u16* __restrict__ k,
                                                  const u16* __restrict__ v,
                                                  u16* __restrict__ ctx) {
    const unsigned wgid = blockIdx.y * gridDim.x + blockIdx.x;
    const unsigned xcd = wgid & 7;
    const unsigned lix = wgid >> 3;
    const unsigned stripe = gridDim.x >> 3;          // bh per XCD (=4)
    const int bh = xcd * stripe + (lix % stripe);    // 0..B*H-1
    const int qt = gridDim.y - 1 - (lix / stripe);   // heavy q-tiles first
    const int b = bh >> 4;              // /HH
    const int hd = bh & 15;             // %HH
    const int qb = qt * 64;
    const int tid = threadIdx.x;
    const int w = tid >> 6;             // wave 0..3
    const int lane = tid & 63;
    const int l15 = lane & 15;
    const int l4 = lane >> 4;           // 0..3
    const int qw = qb + w * 16;         // wave's first query row
    const float scale = 0.125f;         // 1/sqrt(64)

    __shared__ u16 KsS[32 * 64];        // 4KB
    __shared__ u16 VtS[64 * 32];        // 4KB (transposed V)
    __shared__ u16 PwS[4][16 * 32];     // 4KB (per-wave P)
    char* Ks = (char*)KsS;
    char* Vt = (char*)VtS;
    char* Pw = (char*)PwS[w];

    // Q fragments (A operand), held in registers for the whole block
    const size_t qoff = ((size_t)(b * TT + qw + l15)) * CC + hd * DD + l4 * 8;
    const bf16x8 qf0 = *(const bf16x8*)(q + qoff);        // d 0..31 chunk
    const bf16x8 qf1 = *(const bf16x8*)(q + qoff + 32);   // d 32..63 chunk

    f32x4 zero4 = {0.f, 0.f, 0.f, 0.f};
    f32x4 ctxa[4] = {zero4, zero4, zero4, zero4};         // ctx[16 q][64 d]
    float m[4]    = {-1e30f, -1e30f, -1e30f, -1e30f};     // running row max
    float lsum[4] = {0.f, 0.f, 0.f, 0.f};                 // per-lane partial denom

    // block-cooperative staging assignment: thread -> (key row, d-octet)
    const int skey = tid >> 3;          // 0..31
    const int sd8 = tid & 7;            // 0..7
    const int kWByte = skey * 128 + ((sd8 ^ (skey & 7)) << 4);      // swizzled K dest
    const int keyx2 = (skey ^ ((sd8 & 3) << 3)) * 2;                // swizzled Vt key

    const int nt = qt * 2 + 2;          // 32-key tiles covering [0, qb+64)

    uint4 kreg, vreg;                   // register double-buffer for staging
    {
        const size_t g = ((size_t)(b * TT + skey)) * CC + hd * DD + sd8 * 8;
        kreg = *(const uint4*)(k + g);
        vreg = *(const uint4*)(v + g);
    }

    for (int t = 0; t < nt; ++t) {
        const int kv0 = t * 32;
        // ---- write staged regs -> LDS ----
        *(uint4*)(Ks + kWByte) = kreg;
        {
            const u16* vr = (const u16*)&vreg;
#pragma unroll
            for (int j = 0; j < 8; ++j)     // Vt[d][key'] transpose-scatter
                *(u16*)(Vt + (sd8 * 8 + j) * 64 + keyx2) = vr[j];
        }
        __syncthreads();
        // ---- issue next tile's global loads (latency hides under compute) ----
        if (t + 1 < nt) {
            const size_t g = ((size_t)(b * TT + kv0 + 32 + skey)) * CC + hd * DD + sd8 * 8;
            kreg = *(const uint4*)(k + g);
            vreg = *(const uint4*)(v + g);
        }
        if (kv0 <= qw + 15) {   // wave-uniform: skip fully-masked tiles
            // ---- QK^T: S[16 q][32 key], 2 C-tiles x 2 K-chunks ----
            f32x4 s[2];
#pragma unroll
            for (int c = 0; c < 2; ++c) {
                const int key = c * 16 + l15;
                const int kb = key * 128;
                const int kx = key & 7;
                const bf16x8 kf0 = *(const bf16x8*)(Ks + kb + ((l4 ^ kx) << 4));
                const bf16x8 kf1 = *(const bf16x8*)(Ks + kb + (((4 + l4) ^ kx) << 4));
                f32x4 z = {0.f, 0.f, 0.f, 0.f};
                z = __builtin_amdgcn_mfma_f32_16x16x32_bf16(qf0, kf0, z, 0, 0, 0);
                z = __builtin_amdgcn_mfma_f32_16x16x32_bf16(qf1, kf1, z, 0, 0, 0);
                s[c] = z;
            }
            // ---- scale + causal mask (element: key <= row) ----
            float sv[2][4];
#pragma unroll
            for (int c = 0; c < 2; ++c) {
                const int key = kv0 + c * 16 + l15;
#pragma unroll
                for (int r = 0; r < 4; ++r) {
                    const int row = qw + l4 * 4 + r;
                    sv[c][r] = (key <= row) ? s[c][r] * scale : -1e30f;
                }
            }
            // ---- online softmax (row spread over 16 lanes; xor 1/2/4/8 stays in group) ----
#pragma unroll
            for (int r = 0; r < 4; ++r) {
                float mt = fmaxf(sv[0][r], sv[1][r]);
                mt = fmaxf(mt, __shfl_xor(mt, 1, 64));
                mt = fmaxf(mt, __shfl_xor(mt, 2, 64));
                mt = fmaxf(mt, __shfl_xor(mt, 4, 64));
                mt = fmaxf(mt, __shfl_xor(mt, 8, 64));
                const float mn = fmaxf(m[r], mt);
                const float corr = __expf(m[r] - mn);   // 0 on first tile (m=-1e30)
                m[r] = mn;
                const float p0 = __expf(sv[0][r] - mn); // masked -> exp(-1e30)=0
                const float p1 = __expf(sv[1][r] - mn);
                lsum[r] = lsum[r] * corr + p0 + p1;
#pragma unroll
                for (int nb = 0; nb < 4; ++nb) ctxa[nb][r] *= corr;
                const int rowb = (l4 * 4 + r) * 64;
                *(u16*)(Pw + rowb + l15 * 2) = f2bf(p0);
                *(u16*)(Pw + rowb + 32 + l15 * 2) = f2bf(p1);
            }
            // ---- PV: ctx += P[16x32] * V[32x64] ----
            const bf16x8 pf = *(const bf16x8*)(Pw + l15 * 64 + l4 * 16);  // A-frag
#pragma unroll
            for (int nb = 0; nb < 4; ++nb) {
                const int d = nb * 16 + l15;
                const bf16x8 vf = *(const bf16x8*)(Vt + d * 64 + ((l4 ^ ((d >> 3) & 3)) << 4));
                ctxa[nb] = __builtin_amdgcn_mfma_f32_16x16x32_bf16(pf, vf, ctxa[nb], 0, 0, 0);
            }
        }
        __syncthreads();
    }

    // ---- epilogue: reduce denominators across the 16 column lanes, write bf16 ----
    float inv[4];
#pragma unroll
    for (int r = 0; r < 4; ++r) {
        float sred = lsum[r];
        sred += __shfl_xor(sred, 1, 64);
        sred += __shfl_xor(sred, 2, 64);
        sred += __shfl_xor(sred, 4, 64);
        sred += __shfl_xor(sred, 8, 64);
        inv[r] = 1.0f / sred;   // >0: key 0 is always unmasked in tile 0
    }
    u16* cp = ctx + ((size_t)(b * TT + qw)) * CC + hd * DD;
#pragma unroll
    for (int r = 0; r < 4; ++r) {
        const size_t rb = (size_t)(l4 * 4 + r) * CC;
#pragma unroll
        for (int nb = 0; nb < 4; ++nb)
            cp[rb + nb * 16 + l15] = f2bf(ctxa[nb][r] * inv[r]);
    }
}

// ---------- 5. loss: per-row logsumexp + NLL ----------
__global__ __launch_bounds__(256) void loss_row(const void* __restrict__ logits,
                                                const int* __restrict__ target,
                                                float* __restrict__ nll,
                                                const int* __restrict__ flagp) {
    const int f = *flagp;
    const int r = blockIdx.x;
    __shared__ float red[4];
    const float* lpf = (const float*)logits + (size_t)r * VV;
    const u16*   lpb = (const u16*)logits + (size_t)r * VV;

    float lmax = -1e30f;
    if (f) { for (int i = threadIdx.x; i < VV; i += 256) lmax = fmaxf(lmax, lpf[i]); }
    else   { for (int i = threadIdx.x; i < VV; i += 256) lmax = fmaxf(lmax, bf2f(lpb[i])); }
#pragma unroll
    for (int off = 32; off > 0; off >>= 1) lmax = fmaxf(lmax, __shfl_down(lmax, off, 64));
    const int wid = threadIdx.x >> 6, lid = threadIdx.x & 63;
    if (lid == 0) red[wid] = lmax;
    __syncthreads();
    lmax = fmaxf(fmaxf(red[0], red[1]), fmaxf(red[2], red[3]));

    float sum = 0.f;
    if (f) { for (int i = threadIdx.x; i < VV; i += 256) sum += __expf(lpf[i] - lmax); }
    else   { for (int i = threadIdx.x; i < VV; i += 256) sum += __expf(bf2f(lpb[i]) - lmax); }
#pragma unroll
    for (int off = 32; off > 0; off >>= 1) sum += __shfl_down(sum, off, 64);
    __syncthreads();
    if (lid == 0) red[wid] = sum;
    __syncthreads();
    if (threadIdx.x == 0) {
        const float s = red[0] + red[1] + red[2] + red[3];
        const float tl = f ? lpf[target[r]] : bf2f(lpb[target[r]]);
        nll[r] = lmax + __logf(s) - tl;   // = -(log_softmax at target)
    }
}

__global__ __launch_bounds__(256) void loss_final(const float* __restrict__ nll,
                                                  void* __restrict__ out,
                                                  const int* __restrict__ flagp) {
    __shared__ float red[4];
    float s = 0.f;
    for (int i = threadIdx.x; i < MM; i += 256) s += nll[i];
#pragma unroll
    for (int off = 32; off > 0; off >>= 1) s += __shfl_down(s, off, 64);
    if ((threadIdx.x & 63) == 0) red[threadIdx.x >> 6] = s;
    __syncthreads();
    if (threadIdx.x == 0) {
        const float t = (red[0] + red[1] + red[2] + red[3]) / (float)MM;
        if (*flagp) ((float*)out)[(size_t)MM * VV] = t;
        else        ((u16*)out)[(size_t)MM * VV] = f2bf(t);
    }
}

// ---------- launch ----------
extern "C" void kernel_launch(void* const* d_in, const int* in_sizes, int n_in,
                              void* d_out, int out_size, void* d_ws, size_t ws_size,
                              hipStream_t stream) {
    const int* x      = (const int*)d_in[0];
    const int* target = (const int*)d_in[1];
    const void* ew  = d_in[2];
    const void* pos = d_in[3];
    const void* Wq  = d_in[4];
    const void* bq  = d_in[5];
    const void* Wk  = d_in[6];
    const void* bk  = d_in[7];
    const void* Wv  = d_in[8];
    const void* bv  = d_in[9];
    const void* Wo  = d_in[10];
    const void* bo  = d_in[11];
    const void* Wu  = d_in[12];

    int* flagp = (int*)d_ws;   // 4 bytes of workspace: dtype flag

    // bf16 scratch inside d_out (dead until logits GEMM; >=64 MiB both modes):
    u16* outw = (u16*)d_out;
    u16* hB  = outw;                                  // [ 0M,  8M)
    u16* qB  = outw + (size_t)1 * MM * CC;            // [ 8M, 16M)
    u16* kB  = outw + (size_t)2 * MM * CC;            // [16M, 24M)
    u16* vB  = outw + (size_t)3 * MM * CC;            // [24M, 32M)
    u16* ctx = qB;  // flash block writes exactly the (row, head-slice) it read
    // bf16 projection weights in d_out [32M, 48M) (both modes; dead until
    // the logits GEMM, and all consumers run before it):
    const size_t WSZ = (size_t)LL * CC * CC;          // 2M elements = 4MB bf16
    u16* WqB = (u16*)((char*)d_out + (size_t)32 * 1024 * 1024);
    u16* WkB = WqB + WSZ;
    u16* WvB = WkB + WSZ;
    u16* WoB = WvB + WSZ;
    // Scratch inside the consumed embed_w buffer (fp32 mode: 32 MiB; bf16: 16 MiB):
    u16* hScr  = (u16*)ew;                                   // [ 0M,  8M)
    float* nll = (float*)((char*)ew + 12u * 1024 * 1024);    // [12M, 12M+16K)
    u16* WuB   = (u16*)((char*)ew + 16u * 1024 * 1024);      // [16M, 32M) fp32 mode ONLY

    probe_kernel<<<1, 256, 0, stream>>>((const u16*)Wu, flagp);
    embed_kernel<<<MM, 256, 0, stream>>>(x, ew, pos, hB, flagp);  // last read of ew table

    // weight conversion (after embed: WuB overlays the live embedding table)
    cvt_w<<<WSZ / 2048, 256, 0, stream>>>(Wq, WqB, 0, flagp);
    cvt_w<<<WSZ / 2048, 256, 0, stream>>>(Wk, WkB, 0, flagp);
    cvt_w<<<WSZ / 2048, 256, 0, stream>>>(Wv, WvB, 0, flagp);
    cvt_w<<<WSZ / 2048, 256, 0, stream>>>(Wo, WoB, 0, flagp);
    cvt_w<<<(size_t)VV * CC / 2048, 256, 0, stream>>>(Wu, WuB, 1, flagp);  // fp32 mode only

    const dim3 gP(CC / 128, MM / 128);   // projection GEMMs: 8 x 32 blocks
    for (int l = 0; l < LL; ++l) {
        const size_t wOffE = (size_t)l * CC * CC, bOff = (size_t)l * CC;
        gemm_bf16<<<gP, 256, 0, stream>>>(hB, WqB + wOffE, nullptr, qB, bq, bOff, nullptr, MM, CC, CC, 0, flagp);
        gemm_bf16<<<gP, 256, 0, stream>>>(hB, WkB + wOffE, nullptr, kB, bk, bOff, nullptr, MM, CC, CC, 0, flagp);
        gemm_bf16<<<gP, 256, 0, stream>>>(hB, WvB + wOffE, nullptr, vB, bv, bOff, nullptr, MM, CC, CC, 0, flagp);
        flash_attn<<<dim3(BB * HH, TT / 64), 256, 0, stream>>>(qB, kB, vB, ctx);
        // out-proj + residual; last layer writes hScr directly (res from hB)
        u16* outH = (l == LL - 1) ? hScr : hB;
        gemm_bf16<<<gP, 256, 0, stream>>>(ctx, WoB + wOffE, nullptr, outH, bo, bOff, hB, MM, CC, CC, 0, flagp);
    }

    // logits GEMM overwrites d_out (dtype per flag); h already lives in hScr
    gemm_bf16<<<dim3(VV / 128, MM / 128), 256, 0, stream>>>(hScr, WuB, Wu, d_out,
                                                            nullptr, 0, nullptr, MM, VV, CC, 1, flagp);
    loss_row<<<MM, 256, 0, stream>>>(d_out, target, nll, flagp);
    loss_final<<<1, 256, 0, stream>>>(nll, d_out, flagp);
}

// Round 9
// 699.712 us; speedup vs baseline: 1.7008x; 1.0713x over previous
//
#include <hip/hip_runtime.h>

// Problem constants (reference: B=2, T=2048, C=1024, V=8192, L=2, H=16, d=64)
#define BB 2
#define TT 2048
#define CC 1024
#define VV 8192
#define LL 2
#define HH 16
#define DD 64
#define MM (BB * TT) // 4096 rows

// R12 = R11 resubmit (second container infra failure; source re-audited, no
// GPU-fault risk found). R11: fused QKV GEMM. R10 post-mortem: gload_lds
// staging took logits gemm 332->106us (MfmaUtil 27%, theory matched).
// Remaining ~640us: six Q/K/V projections + two Wo gemms at grid=256 =
// 1 block/CU -> no cross-block overlap for the vmcnt drain. Fix: pack
// Wq/Wk/Wv into [L][3C][C] bf16 scratch (cvt_w + srcOff), biases into
// [L][3C] bf16 (cvt_b), one N=3072 GEMM per layer (24x32 = 3 blocks/CU);
// qkv mode routes n>>10 to contiguous qB/kB/vB. A-tile read once not 3x.
using u16 = unsigned short;

typedef short bf16x8 __attribute__((ext_vector_type(8)));   // 8 bf16 = 4 VGPRs
typedef float f32x4 __attribute__((ext_vector_type(4)));    // MFMA accumulator
typedef unsigned int u32x2 __attribute__((ext_vector_type(2)));

__device__ __forceinline__ float bf2f(u16 u) {
    union { unsigned int i; float f; } x;
    x.i = ((unsigned int)u) << 16;
    return x.f;
}
__device__ __forceinline__ u16 f2bf(float f) {
    union { float f; unsigned int i; } x;
    x.f = f;
    unsigned int r = x.i + 0x7fffu + ((x.i >> 16) & 1u); // round-to-nearest-even
    return (u16)(r >> 16);
}

// ---------- 0. dtype probe (resolves fp32-vs-bf16 at runtime) ----------
__global__ __launch_bounds__(256) void probe_kernel(const u16* __restrict__ w,
                                                    int* __restrict__ flag) {
    __shared__ int cnt;
    if (threadIdx.x == 0) cnt = 0;
    __syncthreads();
    int c = 0;
    for (int i = threadIdx.x; i < 4096; i += 256) {
        const u16 u = w[2 * i];
        const int e = (u >> 7) & 0xff;
        if (e >= 125) ++c;
    }
    atomicAdd(&cnt, c);
    __syncthreads();
    if (threadIdx.x == 0) *flag = (cnt > 64) ? 1 : 0;
}

// ---------- 1. embedding + positional -> bf16 h ----------
__global__ __launch_bounds__(256) void embed_kernel(const int* __restrict__ x,
                                                    const void* __restrict__ ew,
                                                    const void* __restrict__ pos,
                                                    u16* __restrict__ h,
                                                    const int* __restrict__ flagp) {
    const int f = *flagp;
    const int i = blockIdx.x;        // token row 0..MM-1
    const int t = i & (TT - 1);      // position within sequence
    const int row = x[i];
    const int c = threadIdx.x * 4;
    float4 e, p;
    if (f) {
        e = *(const float4*)((const float*)ew + (size_t)row * CC + c);
        p = *(const float4*)((const float*)pos + (size_t)t * CC + c);
    } else {
        ushort4 eu = *(const ushort4*)((const u16*)ew + (size_t)row * CC + c);
        ushort4 pu = *(const ushort4*)((const u16*)pos + (size_t)t * CC + c);
        e = make_float4(bf2f(eu.x), bf2f(eu.y), bf2f(eu.z), bf2f(eu.w));
        p = make_float4(bf2f(pu.x), bf2f(pu.y), bf2f(pu.z), bf2f(pu.w));
    }
    ushort4 o;
    o.x = f2bf(e.x + p.x); o.y = f2bf(e.y + p.y);
    o.z = f2bf(e.z + p.z); o.w = f2bf(e.w + p.w);
    *(ushort4*)&h[(size_t)i * CC + c] = o;
}

// ---------- 1b. weight convert: fp32 -> bf16 (or bf16 copy), with src offset ----------
// onlyF=1: write only when flag==1 (dst scratch exists only in fp32 mode).
__global__ __launch_bounds__(256) void cvt_w(const void* __restrict__ src, size_t srcOff,
                                             u16* __restrict__ dst,
                                             int onlyF,
                                             const int* __restrict__ flagp) {
    const int f = *flagp;
    const size_t i = ((size_t)blockIdx.x * 256 + threadIdx.x) * 8;
    if (f) {
        const float* s = (const float*)src + srcOff + i;
        float4 a = *(const float4*)s;
        float4 b = *(const float4*)(s + 4);
        uint4 o;
        o.x = (unsigned)f2bf(a.x) | ((unsigned)f2bf(a.y) << 16);
        o.y = (unsigned)f2bf(a.z) | ((unsigned)f2bf(a.w) << 16);
        o.z = (unsigned)f2bf(b.x) | ((unsigned)f2bf(b.y) << 16);
        o.w = (unsigned)f2bf(b.z) | ((unsigned)f2bf(b.w) << 16);
        *(uint4*)(dst + i) = o;
    } else if (!onlyF) {
        *(uint4*)(dst + i) = *(const uint4*)((const u16*)src + srcOff + i);
    }
}

// ---------- 1c. bias fuse: bq|bk|bv [L][C] -> bQKV [L][3C] bf16 ----------
__global__ __launch_bounds__(256) void cvt_b(const void* __restrict__ bq,
                                             const void* __restrict__ bk,
                                             const void* __restrict__ bv,
                                             u16* __restrict__ dst,
                                             const int* __restrict__ flagp) {
    const int f = *flagp;
    const int j = blockIdx.x * 256 + threadIdx.x;   // 0 .. L*3C-1
    const int l = j / (3 * CC);
    const int r = j - l * 3 * CC;
    const int which = r >> 10;          // 0=q 1=k 2=v
    const int col = r & (CC - 1);
    const void* src = (which == 0) ? bq : (which == 1) ? bk : bv;
    const float v = f ? ((const float*)src)[l * CC + col]
                      : bf2f(((const u16*)src)[l * CC + col]);
    dst[j] = f2bf(v);
}

// ---------- 2. MFMA GEMM: out[m,n] = sum_k A[m,k]*W[n,k] (+bias[n]) (+res[m,n]) ----------
// A bf16 [M,K]; Wc bf16 [N,K]. Walt used when flag==0 (native bf16 weights).
// 128x128 tile, BK=64, 256 threads = 4 waves, each a 64x64 sub-tile (4x4
// f32x4 acc). Staging: global_load_lds width=16 into LINEAR LDS rows (128B);
// source octet pre-swizzled so = o ^ ((row>>1)&7); fragment ds_read_b128
// applies the same XOR -> uniform bank spread. 2 barriers per K-step.
// qkv mode: bias always bf16 (fused scratch); output column block n>>10
// selects the q/k/v buffer (contiguous at outP + (n>>10)*MM*CC).
__global__ __launch_bounds__(256) void gemm_bf16(const u16* __restrict__ A,
                                                 const u16* __restrict__ Wc,
                                                 const void* __restrict__ Walt,
                                                 void* __restrict__ outP,
                                                 const void* __restrict__ bias, size_t bOff,
                                                 const u16* __restrict__ res,
                                                 int M, int N, int K, int outFlagged,
                                                 int qkv,
                                                 const int* __restrict__ flagp) {
    const int f = *flagp;
    const u16* W = (Walt && !f) ? (const u16*)Walt : Wc;

    __shared__ u16 smemU[2][128 * 64];   // 32 KB: As | Bs (linear), epilogue reuse
    u16* As = smemU[0];
    u16* Bs = smemU[1];
    char* AsB = (char*)As;
    char* BsB = (char*)Bs;

    // ---- XCD-aware bijective remap ----
    const unsigned wgid = blockIdx.y * gridDim.x + blockIdx.x;
    const unsigned xcd = wgid & 7;
    const unsigned lix = wgid >> 3;
    const unsigned stripe = gridDim.x >> 3;        // n-blocks per XCD
    const unsigned nb = xcd * stripe + (lix % stripe);
    const unsigned mb = lix / stripe;
    const int m0 = mb * 128, n0 = nb * 128;

    const int tid = threadIdx.x;
    const int w = tid >> 6, lane = tid & 63, l15 = lane & 15, l4 = lane >> 4;
    const int wr = (w >> 1) * 64, wc = (w & 1) * 64;   // wave sub-tile origin

    // staging addresses: instr c stages tile rows [w*32+c*8, +8);
    // lane -> row r = r0 + (lane>>3), dest octet d = lane&7 (linear),
    // source octet so = d ^ ((r>>1)&7)  (inverse of the read-side XOR).
    size_t aBase[4], wBase[4];
    int ldsOff[4];
#pragma unroll
    for (int c = 0; c < 4; ++c) {
        const int r = w * 32 + c * 8 + (lane >> 3);
        const int so = (lane & 7) ^ ((r >> 1) & 7);
        aBase[c] = (size_t)(m0 + r) * K + so * 8;
        wBase[c] = (size_t)(n0 + r) * K + so * 8;
        ldsOff[c] = (w * 32 + c * 8) * 64;   // u16 elements (row*64)
    }

    f32x4 acc[4][4] = {};

    for (int kt = 0; kt < K; kt += 64) {
        __syncthreads();            // previous tile fully consumed
#pragma unroll
        for (int c = 0; c < 4; ++c) {
            __builtin_amdgcn_global_load_lds((const uint4*)(A + aBase[c] + kt),
                                             (uint4*)(As + ldsOff[c]), 16, 0, 0);
            __builtin_amdgcn_global_load_lds((const uint4*)(W + wBase[c] + kt),
                                             (uint4*)(Bs + ldsOff[c]), 16, 0, 0);
        }
        __syncthreads();            // compiler drains vmcnt before barrier
#pragma unroll
        for (int ks = 0; ks < 2; ++ks) {
            bf16x8 af[4], bfr[4];
#pragma unroll
            for (int i = 0; i < 4; ++i) {
                const int ra = wr + i * 16 + l15;
                af[i] = *(const bf16x8*)(AsB + ra * 128 + ((((ks << 2) + l4) ^ ((ra >> 1) & 7)) << 4));
                const int rb = wc + i * 16 + l15;
                bfr[i] = *(const bf16x8*)(BsB + rb * 128 + ((((ks << 2) + l4) ^ ((rb >> 1) & 7)) << 4));
            }
#pragma unroll
            for (int i = 0; i < 4; ++i)
#pragma unroll
                for (int j = 0; j < 4; ++j)
                    acc[i][j] = __builtin_amdgcn_mfma_f32_16x16x32_bf16(af[i], bfr[j], acc[i][j], 0, 0, 0);
        }
    }

    // ---- epilogue: LDS transpose -> vectorized stores ----
    // Per-wave scratch: 16 rows x 68 floats (pad 4 -> bank-shift per row).
    float* eps = (float*)smemU + (size_t)w * 1088;
    // bias for this lane's 4 consecutive columns n = n0+wc+l15*4 .. +3
    float4 bv4 = make_float4(0.f, 0.f, 0.f, 0.f);
    if (bias) {
        const int n = n0 + wc + l15 * 4;
        if (qkv || !f) {
            ushort4 bu = *(const ushort4*)((const u16*)bias + bOff + n);
            bv4 = make_float4(bf2f(bu.x), bf2f(bu.y), bf2f(bu.z), bf2f(bu.w));
        } else {
            bv4 = *(const float4*)((const float*)bias + bOff + n);
        }
    }
#pragma unroll
    for (int i = 0; i < 4; ++i) {
        __syncthreads();    // As/Bs (or prior i scratch) fully consumed by all waves
        // scatter: eps[rr][cc] = value at (row_b = wr+i*16+rr, col_b = wc+cc)
#pragma unroll
        for (int j = 0; j < 4; ++j)
#pragma unroll
            for (int r = 0; r < 4; ++r)
                eps[(l4 * 4 + r) * 68 + j * 16 + l15] = acc[i][j][r];
        __syncthreads();    // emits lgkmcnt(0): writes visible before reads
#pragma unroll
        for (int c = 0; c < 4; ++c) {
            const int rr = l4 + 4 * c;
            float4 v4 = *(const float4*)&eps[rr * 68 + l15 * 4];
            v4.x += bv4.x; v4.y += bv4.y; v4.z += bv4.z; v4.w += bv4.w;
            const int m = m0 + wr + i * 16 + rr;
            const int n = n0 + wc + l15 * 4;
            if (res) {
                ushort4 r4 = *(const ushort4*)&res[(size_t)m * N + n];
                v4.x += bf2f(r4.x); v4.y += bf2f(r4.y);
                v4.z += bf2f(r4.z); v4.w += bf2f(r4.w);
            }
            u32x2 o;
            o.x = (unsigned)f2bf(v4.x) | ((unsigned)f2bf(v4.y) << 16);
            o.y = (unsigned)f2bf(v4.z) | ((unsigned)f2bf(v4.w) << 16);
            if (qkv) {
                // route column block to q/k/v buffer (each MM*CC elements)
                u16* dst = (u16*)outP + (size_t)(n >> 10) * (MM * CC)
                                      + (size_t)m * CC + (n & (CC - 1));
                *(u32x2*)dst = o;
            } else if (outFlagged && f) {
                f32x4 nv = {v4.x, v4.y, v4.z, v4.w};
                __builtin_nontemporal_store(nv, (f32x4*)((float*)outP + (size_t)m * N + n));
            } else {
                u32x2* dst = (u32x2*)((u16*)outP + (size_t)m * N + n);
                if (outFlagged) __builtin_nontemporal_store(o, dst);
                else            *dst = o;
            }
        }
    }
}

// ---------- 3. MFMA flash attention ----------
// XCD remap: XCD x owns head-stripe of 4 bh values -> its K/V hot set is
// 4 x 512KB = 2MB, resident in the per-XCD L2; q-tiles iterate heavy-first.
__global__ __launch_bounds__(256) void flash_attn(const u16* __restrict__ q,
                                                  const u16* __restrict__ k,
                                                  const u16* __restrict__ v,
                                                  u16* __restrict__ ctx) {
    const unsigned wgid = blockIdx.y * gridDim.x + blockIdx.x;
    const unsigned xcd = wgid & 7;
    const unsigned lix = wgid >> 3;
    const unsigned stripe = gridDim.x >> 3;          // bh per XCD (=4)
    const int bh = xcd * stripe + (lix % stripe);    // 0..B*H-1
    const int qt = gridDim.y - 1 - (lix / stripe);   // heavy q-tiles first
    const int b = bh >> 4;              // /HH
    const int hd = bh & 15;             // %HH
    const int qb = qt * 64;
    const int tid = threadIdx.x;
    const int w = tid >> 6;             // wave 0..3
    const int lane = tid & 63;
    const int l15 = lane & 15;
    const int l4 = lane >> 4;           // 0..3
    const int qw = qb + w * 16;         // wave's first query row
    const float scale = 0.125f;         // 1/sqrt(64)

    __shared__ u16 KsS[32 * 64];        // 4KB
    __shared__ u16 VtS[64 * 32];        // 4KB (transposed V)
    __shared__ u16 PwS[4][16 * 32];     // 4KB (per-wave P)
    char* Ks = (char*)KsS;
    char* Vt = (char*)VtS;
    char* Pw = (char*)PwS[w];

    // Q fragments (A operand), held in registers for the whole block
    const size_t qoff = ((size_t)(b * TT + qw + l15)) * CC + hd * DD + l4 * 8;
    const bf16x8 qf0 = *(const bf16x8*)(q + qoff);        // d 0..31 chunk
    const bf16x8 qf1 = *(const bf16x8*)(q + qoff + 32);   // d 32..63 chunk

    f32x4 zero4 = {0.f, 0.f, 0.f, 0.f};
    f32x4 ctxa[4] = {zero4, zero4, zero4, zero4};         // ctx[16 q][64 d]
    float m[4]    = {-1e30f, -1e30f, -1e30f, -1e30f};     // running row max
    float lsum[4] = {0.f, 0.f, 0.f, 0.f};                 // per-lane partial denom

    // block-cooperative staging assignment: thread -> (key row, d-octet)
    const int skey = tid >> 3;          // 0..31
    const int sd8 = tid & 7;            // 0..7
    const int kWByte = skey * 128 + ((sd8 ^ (skey & 7)) << 4);      // swizzled K dest
    const int keyx2 = (skey ^ ((sd8 & 3) << 3)) * 2;                // swizzled Vt key

    const int nt = qt * 2 + 2;          // 32-key tiles covering [0, qb+64)

    uint4 kreg, vreg;                   // register double-buffer for staging
    {
        const size_t g = ((size_t)(b * TT + skey)) * CC + hd * DD + sd8 * 8;
        kreg = *(const uint4*)(k + g);
        vreg = *(const uint4*)(v + g);
    }

    for (int t = 0; t < nt; ++t) {
        const int kv0 = t * 32;
        // ---- write staged regs -> LDS ----
        *(uint4*)(Ks + kWByte) = kreg;
        {
            const u16* vr = (const u16*)&vreg;
#pragma unroll
            for (int j = 0; j < 8; ++j)     // Vt[d][key'] transpose-scatter
                *(u16*)(Vt + (sd8 * 8 + j) * 64 + keyx2) = vr[j];
        }
        __syncthreads();
        // ---- issue next tile's global loads (latency hides under compute) ----
        if (t + 1 < nt) {
            const size_t g = ((size_t)(b * TT + kv0 + 32 + skey)) * CC + hd * DD + sd8 * 8;
            kreg = *(const uint4*)(k + g);
            vreg = *(const uint4*)(v + g);
        }
        if (kv0 <= qw + 15) {   // wave-uniform: skip fully-masked tiles
            // ---- QK^T: S[16 q][32 key], 2 C-tiles x 2 K-chunks ----
            f32x4 s[2];
#pragma unroll
            for (int c = 0; c < 2; ++c) {
                const int key = c * 16 + l15;
                const int kb = key * 128;
                const int kx = key & 7;
                const bf16x8 kf0 = *(const bf16x8*)(Ks + kb + ((l4 ^ kx) << 4));
                const bf16x8 kf1 = *(const bf16x8*)(Ks + kb + (((4 + l4) ^ kx) << 4));
                f32x4 z = {0.f, 0.f, 0.f, 0.f};
                z = __builtin_amdgcn_mfma_f32_16x16x32_bf16(qf0, kf0, z, 0, 0, 0);
                z = __builtin_amdgcn_mfma_f32_16x16x32_bf16(qf1, kf1, z, 0, 0, 0);
                s[c] = z;
            }
            // ---- scale + causal mask (element: key <= row) ----
            float sv[2][4];
#pragma unroll
            for (int c = 0; c < 2; ++c) {
                const int key = kv0 + c * 16 + l15;
#pragma unroll
                for (int r = 0; r < 4; ++r) {
                    const int row = qw + l4 * 4 + r;
                    sv[c][r] = (key <= row) ? s[c][r] * scale : -1e30f;
                }
            }
            // ---- online softmax (row spread over 16 lanes; xor 1/2/4/8 stays in group) ----
#pragma unroll
            for (int r = 0; r < 4; ++r) {
                float mt = fmaxf(sv[0][r], sv[1][r]);
                mt = fmaxf(mt, __shfl_xor(mt, 1, 64));
                mt = fmaxf(mt, __shfl_xor(mt, 2, 64));
                mt = fmaxf(mt, __shfl_xor(mt, 4, 64));
                mt = fmaxf(mt, __shfl_xor(mt, 8, 64));
                const float mn = fmaxf(m[r], mt);
                const float corr = __expf(m[r] - mn);   // 0 on first tile (m=-1e30)
                m[r] = mn;
                const float p0 = __expf(sv[0][r] - mn); // masked -> exp(-1e30)=0
                const float p1 = __expf(sv[1][r] - mn);
                lsum[r] = lsum[r] * corr + p0 + p1;
#pragma unroll
                for (int nb = 0; nb < 4; ++nb) ctxa[nb][r] *= corr;
                const int rowb = (l4 * 4 + r) * 64;
                *(u16*)(Pw + rowb + l15 * 2) = f2bf(p0);
                *(u16*)(Pw + rowb + 32 + l15 * 2) = f2bf(p1);
            }
            // ---- PV: ctx += P[16x32] * V[32x64] ----
            const bf16x8 pf = *(const bf16x8*)(Pw + l15 * 64 + l4 * 16);  // A-frag
#pragma unroll
            for (int nb = 0; nb < 4; ++nb) {
                const int d = nb * 16 + l15;
                const bf16x8 vf = *(const bf16x8*)(Vt + d * 64 + ((l4 ^ ((d >> 3) & 3)) << 4));
                ctxa[nb] = __builtin_amdgcn_mfma_f32_16x16x32_bf16(pf, vf, ctxa[nb], 0, 0, 0);
            }
        }
        __syncthreads();
    }

    // ---- epilogue: reduce denominators across the 16 column lanes, write bf16 ----
    float inv[4];
#pragma unroll
    for (int r = 0; r < 4; ++r) {
        float sred = lsum[r];
        sred += __shfl_xor(sred, 1, 64);
        sred += __shfl_xor(sred, 2, 64);
        sred += __shfl_xor(sred, 4, 64);
        sred += __shfl_xor(sred, 8, 64);
        inv[r] = 1.0f / sred;   // >0: key 0 is always unmasked in tile 0
    }
    u16* cp = ctx + ((size_t)(b * TT + qw)) * CC + hd * DD;
#pragma unroll
    for (int r = 0; r < 4; ++r) {
        const size_t rb = (size_t)(l4 * 4 + r) * CC;
#pragma unroll
        for (int nb = 0; nb < 4; ++nb)
            cp[rb + nb * 16 + l15] = f2bf(ctxa[nb][r] * inv[r]);
    }
}

// ---------- 5. loss: per-row logsumexp + NLL ----------
__global__ __launch_bounds__(256) void loss_row(const void* __restrict__ logits,
                                                const int* __restrict__ target,
                                                float* __restrict__ nll,
                                                const int* __restrict__ flagp) {
    const int f = *flagp;
    const int r = blockIdx.x;
    __shared__ float red[4];
    const float* lpf = (const float*)logits + (size_t)r * VV;
    const u16*   lpb = (const u16*)logits + (size_t)r * VV;

    float lmax = -1e30f;
    if (f) { for (int i = threadIdx.x; i < VV; i += 256) lmax = fmaxf(lmax, lpf[i]); }
    else   { for (int i = threadIdx.x; i < VV; i += 256) lmax = fmaxf(lmax, bf2f(lpb[i])); }
#pragma unroll
    for (int off = 32; off > 0; off >>= 1) lmax = fmaxf(lmax, __shfl_down(lmax, off, 64));
    const int wid = threadIdx.x >> 6, lid = threadIdx.x & 63;
    if (lid == 0) red[wid] = lmax;
    __syncthreads();
    lmax = fmaxf(fmaxf(red[0], red[1]), fmaxf(red[2], red[3]));

    float sum = 0.f;
    if (f) { for (int i = threadIdx.x; i < VV; i += 256) sum += __expf(lpf[i] - lmax); }
    else   { for (int i = threadIdx.x; i < VV; i += 256) sum += __expf(bf2f(lpb[i]) - lmax); }
#pragma unroll
    for (int off = 32; off > 0; off >>= 1) sum += __shfl_down(sum, off, 64);
    __syncthreads();
    if (lid == 0) red[wid] = sum;
    __syncthreads();
    if (threadIdx.x == 0) {
        const float s = red[0] + red[1] + red[2] + red[3];
        const float tl = f ? lpf[target[r]] : bf2f(lpb[target[r]]);
        nll[r] = lmax + __logf(s) - tl;   // = -(log_softmax at target)
    }
}

__global__ __launch_bounds__(256) void loss_final(const float* __restrict__ nll,
                                                  void* __restrict__ out,
                                                  const int* __restrict__ flagp) {
    __shared__ float red[4];
    float s = 0.f;
    for (int i = threadIdx.x; i < MM; i += 256) s += nll[i];
#pragma unroll
    for (int off = 32; off > 0; off >>= 1) s += __shfl_down(s, off, 64);
    if ((threadIdx.x & 63) == 0) red[threadIdx.x >> 6] = s;
    __syncthreads();
    if (threadIdx.x == 0) {
        const float t = (red[0] + red[1] + red[2] + red[3]) / (float)MM;
        if (*flagp) ((float*)out)[(size_t)MM * VV] = t;
        else        ((u16*)out)[(size_t)MM * VV] = f2bf(t);
    }
}

// ---------- launch ----------
extern "C" void kernel_launch(void* const* d_in, const int* in_sizes, int n_in,
                              void* d_out, int out_size, void* d_ws, size_t ws_size,
                              hipStream_t stream) {
    const int* x      = (const int*)d_in[0];
    const int* target = (const int*)d_in[1];
    const void* ew  = d_in[2];
    const void* pos = d_in[3];
    const void* Wq  = d_in[4];
    const void* bq  = d_in[5];
    const void* Wk  = d_in[6];
    const void* bk  = d_in[7];
    const void* Wv  = d_in[8];
    const void* bv  = d_in[9];
    const void* Wo  = d_in[10];
    const void* bo  = d_in[11];
    const void* Wu  = d_in[12];

    int* flagp = (int*)d_ws;   // 4 bytes of workspace: dtype flag

    // bf16 scratch inside d_out (dead until logits GEMM; >=64 MiB both modes):
    u16* outw = (u16*)d_out;
    u16* hB  = outw;                                  // [ 0M,  8M)
    u16* qB  = outw + (size_t)1 * MM * CC;            // [ 8M, 16M)
    u16* kB  = outw + (size_t)2 * MM * CC;            // [16M, 24M)
    u16* vB  = outw + (size_t)3 * MM * CC;            // [24M, 32M)
    u16* ctx = qB;  // flash block writes exactly the (row, head-slice) it read
    // fused QKV weights [L][3C][C] bf16 in d_out [32M, 44M); Wo [44M, 48M):
    u16* WqkvB = (u16*)((char*)d_out + (size_t)32 * 1024 * 1024);
    u16* WoB   = (u16*)((char*)d_out + (size_t)44 * 1024 * 1024);
    // Scratch inside the consumed embed_w buffer (fp32 mode: 32 MiB; bf16: 16 MiB):
    u16* hScr  = (u16*)ew;                                   // [ 0M,  8M)
    float* nll = (float*)((char*)ew + 12u * 1024 * 1024);    // [12M, 12M+16K)
    u16* bQKV  = (u16*)((char*)ew + 13u * 1024 * 1024);      // [13M, 13M+12K)
    u16* WuB   = (u16*)((char*)ew + 16u * 1024 * 1024);      // [16M, 32M) fp32 mode ONLY

    probe_kernel<<<1, 256, 0, stream>>>((const u16*)Wu, flagp);
    embed_kernel<<<MM, 256, 0, stream>>>(x, ew, pos, hB, flagp);  // last read of ew table

    // weight conversion (after embed: bQKV/WuB overlay the consumed ew buffer)
    const size_t C2 = (size_t)CC * CC;   // 1M elements per matrix per layer
    for (int l = 0; l < LL; ++l) {
        cvt_w<<<C2 / 2048, 256, 0, stream>>>(Wq, l * C2, WqkvB + l * 3 * C2 + 0 * C2, 0, flagp);
        cvt_w<<<C2 / 2048, 256, 0, stream>>>(Wk, l * C2, WqkvB + l * 3 * C2 + 1 * C2, 0, flagp);
        cvt_w<<<C2 / 2048, 256, 0, stream>>>(Wv, l * C2, WqkvB + l * 3 * C2 + 2 * C2, 0, flagp);
    }
    cvt_w<<<LL * C2 / 2048, 256, 0, stream>>>(Wo, 0, WoB, 0, flagp);
    cvt_w<<<(size_t)VV * CC / 2048, 256, 0, stream>>>(Wu, 0, WuB, 1, flagp);  // fp32 mode only
    cvt_b<<<LL * 3 * CC / 256, 256, 0, stream>>>(bq, bk, bv, bQKV, flagp);

    const dim3 gQKV(3 * CC / 128, MM / 128);   // 24 x 32 = 768 blocks (3/CU)
    const dim3 gP(CC / 128, MM / 128);         // 8 x 32 = 256 blocks
    for (int l = 0; l < LL; ++l) {
        const size_t bOff = (size_t)l * CC;
        // fused QKV projection: writes qB|kB|vB via column-block routing
        gemm_bf16<<<gQKV, 256, 0, stream>>>(hB, WqkvB + (size_t)l * 3 * C2, nullptr, qB,
                                            bQKV, (size_t)l * 3 * CC, nullptr,
                                            MM, 3 * CC, CC, 0, 1, flagp);
        flash_attn<<<dim3(BB * HH, TT / 64), 256, 0, stream>>>(qB, kB, vB, ctx);
        // out-proj + residual; last layer writes hScr directly (res from hB)
        u16* outH = (l == LL - 1) ? hScr : hB;
        gemm_bf16<<<gP, 256, 0, stream>>>(ctx, WoB + (size_t)l * C2, nullptr, outH, bo, bOff, hB,
                                          MM, CC, CC, 0, 0, flagp);
    }

    // logits GEMM overwrites d_out (dtype per flag); h already lives in hScr
    gemm_bf16<<<dim3(VV / 128, MM / 128), 256, 0, stream>>>(hScr, WuB, Wu, d_out,
                                                            nullptr, 0, nullptr,
                                                            MM, VV, CC, 1, 0, flagp);
    loss_row<<<MM, 256, 0, stream>>>(d_out, target, nll, flagp);
    loss_final<<<1, 256, 0, stream>>>(nll, d_out, flagp);
}